// Round 12
// baseline (899.097 us; speedup 1.0000x reference)
//
#include <hip/hip_runtime.h>
#include <math.h>

#define NN 50000
#define NPAD 50048            // 391 * 128
#define EE 800000
#define HH 4
#define DD 128
#define HDIM 512
#define LL 4

typedef __attribute__((ext_vector_type(8))) short short8;
typedef __attribute__((ext_vector_type(4))) float f32x4;

__device__ __forceinline__ float lk(float x, float s){ return x > 0.f ? x : s*x; }
__device__ __forceinline__ unsigned short f2bf(float f){
  unsigned u = __float_as_uint(f);
  u += 0x7FFFu + ((u >> 16) & 1u);
  return (unsigned short)(u >> 16);
}
__device__ __forceinline__ float lo16(unsigned u){ return __uint_as_float(u << 16); }
__device__ __forceinline__ float hi16(unsigned u){ return __uint_as_float(u & 0xFFFF0000u); }

// ---------------- CSR build ---------------------------------------------------------------------
__global__ void k_zero(int* p, int n){ int i = blockIdx.x*blockDim.x+threadIdx.x; if(i<n) p[i]=0; }

__global__ void k_hist(const int* __restrict__ dst, int* __restrict__ cnt){
  int e = blockIdx.x*blockDim.x+threadIdx.x;
  if (e < EE) atomicAdd(&cnt[dst[e]], 1);
}

// scan writes BOTH row_ptr and cursor (k_copy folded in)
__global__ __launch_bounds__(1024) void k_scan(const int* __restrict__ cnt,
                                               int* __restrict__ row_ptr,
                                               int* __restrict__ cursor){
  __shared__ int part[1024];
  int t = threadIdx.x;
  const int chunk = (NN + 1023)/1024;
  int b = t*chunk, e = b+chunk;
  if (b > NN) b = NN;
  if (e > NN) e = NN;
  int s = 0;
  for (int i=b;i<e;++i) s += cnt[i];
  part[t] = s;
  __syncthreads();
  for (int off=1; off<1024; off<<=1){
    int v = (t>=off) ? part[t-off] : 0;
    __syncthreads();
    part[t] += v;
    __syncthreads();
  }
  int run = part[t] - s;
  for (int i=b;i<e;++i){ row_ptr[i] = run; cursor[i] = run; run += cnt[i]; }
  if (t==1023) row_ptr[NN] = part[1023];
}

__global__ void k_fill(const int* __restrict__ src, const int* __restrict__ dst,
                       int* __restrict__ cursor, int* __restrict__ csr_src){
  int e = blockIdx.x*blockDim.x+threadIdx.x;
  if (e >= EE) return;
  int d = dst[e];
  int p = atomicAdd(&cursor[d], 1);
  csr_src[p] = src[e];
}

// ---------------- weight transposes via LDS tiles (coalesced both sides) -----------------------
__global__ __launch_bounds__(256) void k_cvtw2(const float* __restrict__ Wf,
                                               const float* __restrict__ Wr,
                                               unsigned short* __restrict__ W2t){
  __shared__ float tile[64][65];
  int t = threadIdx.x;
  int n0 = blockIdx.x*64, k0 = blockIdx.y*64, l = blockIdx.z;
  const float* srcp = (n0 < 512) ? Wf : Wr;
  int nsrc = (n0 < 512) ? n0 : (n0 - 512);
  #pragma unroll
  for (int j=0;j<16;++j){
    int idx = t + j*256; int kk = idx>>6, nn = idx&63;
    tile[kk][nn] = srcp[(size_t)(l*128 + k0+kk)*512 + nsrc+nn];
  }
  __syncthreads();
  #pragma unroll
  for (int j=0;j<16;++j){
    int idx = t + j*256; int nn = idx>>6, kk = idx&63;
    W2t[((size_t)l*1024 + n0+nn)*128 + k0+kk] = f2bf(tile[kk][nn]);
  }
}
__global__ __launch_bounds__(256) void k_cvtwn(const float* __restrict__ Wn,
                                               unsigned short* __restrict__ Wnt){
  __shared__ float tile[64][65];
  int t = threadIdx.x;
  int n0 = blockIdx.x*64, k0 = blockIdx.y*64, l = blockIdx.z;
  #pragma unroll
  for (int j=0;j<16;++j){
    int idx = t + j*256; int kk = idx>>6, nn = idx&63;
    tile[kk][nn] = Wn[(size_t)(l*512 + k0+kk)*128 + n0+nn];
  }
  __syncthreads();
  #pragma unroll
  for (int j=0;j<16;++j){
    int idx = t + j*256; int nn = idx>>6, kk = idx&63;
    Wnt[((size_t)l*128 + n0+nn)*512 + k0+kk] = f2bf(tile[kk][nn]);
  }
}
__global__ void k_cvtx(const float* __restrict__ x, unsigned short* __restrict__ xb){
  int idx = blockIdx.x*blockDim.x + threadIdx.x;
  int row = idx >> 7;
  xb[idx] = (row < NN) ? f2bf(x[idx]) : (unsigned short)0;
}

// ---------------- GEMM1 (MFMA): A fragments register-cached, nb-loop over 4 N-tiles ------------
// grid (NPAD/128, 2). y=0: feat heads 0-3 (int8 quant + el/er epilogue). y=1: res -> hbuf bf16.
// sA is immutable after staging -> af[4][4] hoisted to registers; inner loop reads only sB.
__global__ __launch_bounds__(256) void k_gemm1m(const unsigned short* __restrict__ xb,
                                                const unsigned short* __restrict__ W2t,
                                                const float* __restrict__ al,
                                                const float* __restrict__ ar,
                                                unsigned char* __restrict__ featQ,
                                                unsigned short* __restrict__ hbuf,
                                                float2* __restrict__ elsc,
                                                float* __restrict__ erp){
  __shared__ __attribute__((aligned(16))) unsigned short sA[128*136];
  __shared__ __attribute__((aligned(16))) unsigned short sB[128*136];
  __shared__ float sAl[512], sAr[512], sInv[128];
  int t = threadIdx.x;
  int m0 = blockIdx.x*128;
  int isRes = blockIdx.y;                        // 0 feat / 1 res
  if (!isRes){
    sAl[t] = al[t]; sAl[256+t] = al[256+t];
    sAr[t] = ar[t]; sAr[256+t] = ar[256+t];
  }
  #pragma unroll
  for (int j=0;j<8;++j){
    int c = t + j*256; int r = c>>4, kc = c&15;
    uint4 v = *(const uint4*)(xb + (size_t)(m0+r)*128 + kc*8);
    *(uint4*)(sA + r*136 + kc*8) = v;
  }
  __syncthreads();

  int lane = t & 63, w = t >> 6;
  int wm = (w & 1)*64, wn = (w >> 1)*64;
  int lrow = lane & 15, quad = lane >> 4;

  // hoist all A fragments to registers (sA constant hereafter)
  short8 af[4][4];                               // [kq][mt]
  #pragma unroll
  for (int kq=0;kq<4;++kq){
    int kb = kq*32 + quad*8;
    #pragma unroll
    for (int mt=0;mt<4;++mt) af[kq][mt] = *(const short8*)(sA + (wm+mt*16+lrow)*136 + kb);
  }

  for (int nb=0; nb<4; ++nb){
    int n0 = isRes*512 + nb*128;
    if (nb) __syncthreads();                     // prev epilogue reads of sB done
    #pragma unroll
    for (int j=0;j<8;++j){
      int c = t + j*256; int r = c>>4, kc = c&15;
      uint4 v = *(const uint4*)(W2t + (size_t)(n0+r)*128 + kc*8);
      *(uint4*)(sB + r*136 + kc*8) = v;
    }
    __syncthreads();

    f32x4 acc[4][4];
    #pragma unroll
    for (int mt=0;mt<4;++mt)
      #pragma unroll
      for (int nt=0;nt<4;++nt) acc[mt][nt] = (f32x4){0.f,0.f,0.f,0.f};

    #pragma unroll
    for (int kq=0;kq<4;++kq){
      int kb = kq*32 + quad*8;
      short8 bf[4];
      #pragma unroll
      for (int nt=0;nt<4;++nt) bf[nt] = *(const short8*)(sB + (wn+nt*16+lrow)*136 + kb);
      #pragma unroll
      for (int mt=0;mt<4;++mt)
        #pragma unroll
        for (int nt=0;nt<4;++nt)
          acc[mt][nt] = __builtin_amdgcn_mfma_f32_16x16x32_bf16(af[kq][mt], bf[nt], acc[mt][nt], 0,0,0);
    }

    __syncthreads();                             // all MFMA reads of sB done -> reuse for C
    #pragma unroll
    for (int mt=0;mt<4;++mt)
      #pragma unroll
      for (int nt=0;nt<4;++nt)
        #pragma unroll
        for (int r=0;r<4;++r)
          sB[(wm+mt*16+quad*4+r)*136 + wn+nt*16+lrow] = f2bf(acc[mt][nt][r]);
    __syncthreads();

    if (isRes){
      #pragma unroll
      for (int j=0;j<8;++j){
        int c = t + j*256; int r = c>>4, kc = c&15;
        uint4 v = *(const uint4*)(sB + r*136 + kc*8);
        *(uint4*)(hbuf + (size_t)(m0+r)*512 + nb*128 + kc*8) = v;
      }
    } else {
      // el/er logits + head-row amax (2 threads per row, 64 ch each); head = nb
      int r = t >> 1, half = t & 1;
      int base = half*64;
      float accl = 0.f, accr = 0.f, amax = 0.f;
      #pragma unroll
      for (int d=0; d<64; d+=4){
        uint2 u = *(const uint2*)&sB[r*136 + base + d];
        float f0=lo16(u.x), f1=hi16(u.x), f2=lo16(u.y), f3=hi16(u.y);
        float4 a  = *(const float4*)&sAl[nb*128 + base + d];
        float4 rr = *(const float4*)&sAr[nb*128 + base + d];
        accl += f0*a.x + f1*a.y + f2*a.z + f3*a.w;
        accr += f0*rr.x + f1*rr.y + f2*rr.z + f3*rr.w;
        amax = fmaxf(amax, fmaxf(fmaxf(fabsf(f0), fabsf(f1)), fmaxf(fabsf(f2), fabsf(f3))));
      }
      accl += __shfl_xor(accl, 1);
      accr += __shfl_xor(accr, 1);
      amax = fmaxf(amax, __shfl_xor(amax, 1));
      float am = fmaxf(amax, 1e-8f);
      if (half == 0){
        sInv[r] = 127.f / am;
        if ((m0+r) < NN){
          elsc[(size_t)(m0+r)*4 + nb] = make_float2(accl, am * (1.f/127.f));
          erp[(size_t)(m0+r)*4 + nb] = accr;
        }
      }
      __syncthreads();
      float qinv = sInv[r];
      unsigned char* qdst = featQ + (size_t)(m0+r)*512 + nb*128 + base;
      #pragma unroll
      for (int g=0; g<4; ++g){
        uint4 ua = *(const uint4*)&sB[r*136 + base + g*16];
        uint4 ub = *(const uint4*)&sB[r*136 + base + g*16 + 8];
        unsigned vals[8] = {ua.x, ua.y, ua.z, ua.w, ub.x, ub.y, ub.z, ub.w};
        unsigned p[4];
        #pragma unroll
        for (int j=0;j<4;++j){
          unsigned vlo = vals[2*j], vhi = vals[2*j+1];
          int q0 = (int)rintf(lo16(vlo)*qinv) + 128;
          int q1 = (int)rintf(hi16(vlo)*qinv) + 128;
          int q2 = (int)rintf(lo16(vhi)*qinv) + 128;
          int q3 = (int)rintf(hi16(vhi)*qinv) + 128;
          p[j] = (unsigned)q0 | ((unsigned)q1<<8) | ((unsigned)q2<<16) | ((unsigned)q3<<24);
        }
        *(uint4*)(qdst + g*16) = make_uint4(p[0],p[1],p[2],p[3]);
      }
    }
  }
}

// ---------------- edge softmax + aggregation: int8 gather, single pass, 4x unroll --------------
__global__ __launch_bounds__(256) void k_agg(const unsigned char* __restrict__ featQ,
                                             unsigned short* __restrict__ hbuf,
                                             const float2* __restrict__ elsc,
                                             const float* __restrict__ er,
                                             const int* __restrict__ row_ptr,
                                             const int* __restrict__ csr_src,
                                             const float* __restrict__ b_gat){
  int t = threadIdx.x;
  int lane = t & 63;
  int node = blockIdx.x*4 + (t>>6);              // NN % 4 == 0, grid exact
  int beg = row_ptr[node], end = row_ptr[node+1];
  int hd = lane >> 4;
  float erh = er[(size_t)node*4 + hd];

  float z = 0.f, sws = 0.f;
  float a0=0.f,a1=0.f,a2=0.f,a3=0.f,a4=0.f,a5=0.f,a6=0.f,a7=0.f;
  const uint2* fQ = (const uint2*)featQ;         // row = 64 uint2 (512 bytes)

  int i = beg;
  for (; i + 3 < end; i += 4){
    int s0 = csr_src[i], s1 = csr_src[i+1], s2 = csr_src[i+2], s3 = csr_src[i+3];
    float2 q0 = elsc[(size_t)s0*4 + hd];
    float2 q1 = elsc[(size_t)s1*4 + hd];
    float2 q2 = elsc[(size_t)s2*4 + hd];
    float2 q3 = elsc[(size_t)s3*4 + hd];
    uint2 f0 = fQ[(size_t)s0*64 + lane];
    uint2 f1 = fQ[(size_t)s1*64 + lane];
    uint2 f2 = fQ[(size_t)s2*64 + lane];
    uint2 f3 = fQ[(size_t)s3*64 + lane];
    float w0 = __expf(lk(q0.x + erh, 0.2f));
    float w1 = __expf(lk(q1.x + erh, 0.2f));
    float w2 = __expf(lk(q2.x + erh, 0.2f));
    float w3 = __expf(lk(q3.x + erh, 0.2f));
    float ws0 = w0*q0.y, ws1 = w1*q1.y, ws2 = w2*q2.y, ws3 = w3*q3.y;
    z += w0 + w1 + w2 + w3;
    sws += ws0 + ws1 + ws2 + ws3;
    a0 += ws0*(float)(f0.x & 255u)      + ws1*(float)(f1.x & 255u)      + ws2*(float)(f2.x & 255u)      + ws3*(float)(f3.x & 255u);
    a1 += ws0*(float)((f0.x>>8) & 255u) + ws1*(float)((f1.x>>8) & 255u) + ws2*(float)((f2.x>>8) & 255u) + ws3*(float)((f3.x>>8) & 255u);
    a2 += ws0*(float)((f0.x>>16)& 255u) + ws1*(float)((f1.x>>16)& 255u) + ws2*(float)((f2.x>>16)& 255u) + ws3*(float)((f3.x>>16)& 255u);
    a3 += ws0*(float)(f0.x>>24)         + ws1*(float)(f1.x>>24)         + ws2*(float)(f2.x>>24)         + ws3*(float)(f3.x>>24);
    a4 += ws0*(float)(f0.y & 255u)      + ws1*(float)(f1.y & 255u)      + ws2*(float)(f2.y & 255u)      + ws3*(float)(f3.y & 255u);
    a5 += ws0*(float)((f0.y>>8) & 255u) + ws1*(float)((f1.y>>8) & 255u) + ws2*(float)((f2.y>>8) & 255u) + ws3*(float)((f3.y>>8) & 255u);
    a6 += ws0*(float)((f0.y>>16)& 255u) + ws1*(float)((f1.y>>16)& 255u) + ws2*(float)((f2.y>>16)& 255u) + ws3*(float)((f3.y>>16)& 255u);
    a7 += ws0*(float)(f0.y>>24)         + ws1*(float)(f1.y>>24)         + ws2*(float)(f2.y>>24)         + ws3*(float)(f3.y>>24);
  }
  for (; i < end; ++i){
    int s = csr_src[i];
    float2 q = elsc[(size_t)s*4 + hd];
    uint2 f = fQ[(size_t)s*64 + lane];
    float w = __expf(lk(q.x + erh, 0.2f));
    float ws = w*q.y;
    z += w; sws += ws;
    a0 += ws*(float)(f.x & 255u);       a1 += ws*(float)((f.x>>8) & 255u);
    a2 += ws*(float)((f.x>>16) & 255u); a3 += ws*(float)(f.x>>24);
    a4 += ws*(float)(f.y & 255u);       a5 += ws*(float)((f.y>>8) & 255u);
    a6 += ws*(float)((f.y>>16) & 255u); a7 += ws*(float)(f.y>>24);
  }
  float iz = 1.f / fmaxf(z, 1e-20f);
  float off = 128.f * sws;

  uint4* rp = (uint4*)(hbuf + (size_t)node*HDIM) + lane;
  uint4 rv = *rp;
  const float4* bp = (const float4*)b_gat;
  float4 b1 = bp[2*lane], b2 = bp[2*lane+1];
  float o0 = lk((a0-off)*iz + lo16(rv.x) + b1.x, 0.01f);
  float o1 = lk((a1-off)*iz + hi16(rv.x) + b1.y, 0.01f);
  float o2 = lk((a2-off)*iz + lo16(rv.y) + b1.z, 0.01f);
  float o3 = lk((a3-off)*iz + hi16(rv.y) + b1.w, 0.01f);
  float o4 = lk((a4-off)*iz + lo16(rv.z) + b2.x, 0.01f);
  float o5 = lk((a5-off)*iz + hi16(rv.z) + b2.y, 0.01f);
  float o6 = lk((a6-off)*iz + lo16(rv.w) + b2.z, 0.01f);
  float o7 = lk((a7-off)*iz + hi16(rv.w) + b2.w, 0.01f);
  uint4 wv;
  wv.x = (unsigned)f2bf(o0) | ((unsigned)f2bf(o1) << 16);
  wv.y = (unsigned)f2bf(o2) | ((unsigned)f2bf(o3) << 16);
  wv.z = (unsigned)f2bf(o4) | ((unsigned)f2bf(o5) << 16);
  wv.w = (unsigned)f2bf(o6) | ((unsigned)f2bf(o7) << 16);
  *rp = wv;
}

// ---------------- GEMM3 (MFMA, K=512) + LayerNorm; A and B both LDS-staged ---------------------
__global__ __launch_bounds__(256) void k_gemm3m(const unsigned short* __restrict__ h,
                                                const unsigned short* __restrict__ Wnt,
                                                const float* __restrict__ bn,
                                                const float* __restrict__ lng,
                                                const float* __restrict__ lnb,
                                                float* __restrict__ out,
                                                unsigned short* __restrict__ xb,
                                                int writeOut){
  __shared__ __attribute__((aligned(16))) char smem[2*128*136*2];
  unsigned short* sA = (unsigned short*)smem;
  unsigned short* sB = sA + 128*136;
  float* yf = (float*)smem;
  int t = threadIdx.x;
  int m0 = blockIdx.x*128;
  int lane = t & 63, w = t >> 6;
  int wm = (w & 1)*64, wn = (w >> 1)*64;
  int lrow = lane & 15, quad = lane >> 4;

  f32x4 acc[4][4];
  #pragma unroll
  for (int mt=0;mt<4;++mt)
    #pragma unroll
    for (int nt=0;nt<4;++nt) acc[mt][nt] = (f32x4){0.f,0.f,0.f,0.f};

  for (int kc2=0; kc2<4; ++kc2){
    if (kc2) __syncthreads();
    #pragma unroll
    for (int j=0;j<8;++j){
      int c = t + j*256; int r = c>>4, kc = c&15;
      uint4 v = *(const uint4*)(h + (size_t)(m0+r)*512 + kc2*128 + kc*8);
      *(uint4*)(sA + r*136 + kc*8) = v;
    }
    #pragma unroll
    for (int j=0;j<8;++j){
      int c = t + j*256; int r = c>>4, kc = c&15;
      uint4 v = *(const uint4*)(Wnt + (size_t)r*512 + kc2*128 + kc*8);
      *(uint4*)(sB + r*136 + kc*8) = v;
    }
    __syncthreads();
    #pragma unroll
    for (int kq=0;kq<4;++kq){
      int kb = kq*32 + quad*8;
      short8 af[4], bf[4];
      #pragma unroll
      for (int mt=0;mt<4;++mt) af[mt] = *(const short8*)(sA + (wm+mt*16+lrow)*136 + kb);
      #pragma unroll
      for (int nt=0;nt<4;++nt) bf[nt] = *(const short8*)(sB + (wn+nt*16+lrow)*136 + kb);
      #pragma unroll
      for (int mt=0;mt<4;++mt)
        #pragma unroll
        for (int nt=0;nt<4;++nt)
          acc[mt][nt] = __builtin_amdgcn_mfma_f32_16x16x32_bf16(af[mt], bf[nt], acc[mt][nt], 0,0,0);
    }
  }

  float bnv[4];
  #pragma unroll
  for (int nt=0;nt<4;++nt) bnv[nt] = bn[wn + nt*16 + lrow];
  __syncthreads();
  #pragma unroll
  for (int mt=0;mt<4;++mt)
    #pragma unroll
    for (int nt=0;nt<4;++nt)
      #pragma unroll
      for (int r=0;r<4;++r)
        yf[(wm+mt*16+quad*4+r)*132 + wn+nt*16+lrow] = acc[mt][nt][r] + bnv[nt];
  __syncthreads();

  float g0 = lng[lane], g1 = lng[64+lane];
  float bb0 = lnb[lane], bb1 = lnb[64+lane];
  for (int rr = w*32; rr < w*32+32; ++rr){
    float v0 = yf[rr*132 + lane], v1 = yf[rr*132 + 64 + lane];
    float s = v0 + v1;
    #pragma unroll
    for (int off=32; off>0; off>>=1) s += __shfl_xor(s, off);
    float mu = s * (1.f/128.f);
    float d0 = v0-mu, d1 = v1-mu;
    float q = d0*d0 + d1*d1;
    #pragma unroll
    for (int off=32; off>0; off>>=1) q += __shfl_xor(q, off);
    float inv = rsqrtf(q*(1.f/128.f) + 1e-5f);
    int grow = m0 + rr;
    if (grow < NN){
      float o0 = d0*inv*g0 + bb0;
      float o1 = d1*inv*g1 + bb1;
      xb[(size_t)grow*128 + lane]      = f2bf(o0);
      xb[(size_t)grow*128 + 64 + lane] = f2bf(o1);
      if (writeOut){
        out[(size_t)grow*128 + lane]      = o0;
        out[(size_t)grow*128 + 64 + lane] = o1;
      }
    }
  }
}

extern "C" void kernel_launch(void* const* d_in, const int* in_sizes, int n_in,
                              void* d_out, int out_size, void* d_ws, size_t ws_size,
                              hipStream_t stream){
  const float* features = (const float*)d_in[0];
  const int*   src      = (const int*)d_in[1];
  const int*   dst      = (const int*)d_in[2];
  const float* W_fc     = (const float*)d_in[3];
  const float* attn_l   = (const float*)d_in[4];
  const float* attn_r   = (const float*)d_in[5];
  const float* W_res    = (const float*)d_in[6];
  const float* b_gat    = (const float*)d_in[7];
  const float* W_nrm    = (const float*)d_in[8];
  const float* b_nrm    = (const float*)d_in[9];
  const float* ln_g     = (const float*)d_in[10];
  const float* ln_b     = (const float*)d_in[11];
  float* out = (float*)d_out;

  // workspace (~97 MB)
  unsigned short* xb    = (unsigned short*)d_ws;            // [NPAD,128] bf16
  unsigned short* hbuf  = xb + (size_t)NPAD*128;            // [NPAD,512] bf16 (res -> h)
  unsigned short* W2t   = hbuf + (size_t)NPAD*512;          // [L,1024,128] bf16
  unsigned short* Wnt   = W2t + (size_t)LL*1024*128;        // [L,128,512] bf16
  unsigned char* featQ  = (unsigned char*)(Wnt + (size_t)LL*128*512);  // [NPAD,512] u8
  float2* elsc = (float2*)(featQ + (size_t)NPAD*512);       // [N,4] {el, scale}
  float* er = (float*)(elsc + (size_t)NN*4);                // [N,4]
  int* row_ptr = (int*)(er + (size_t)NN*4);                 // N+1
  int* cursor  = row_ptr + (NN+1);                          // N
  int* csr_src = cursor + NN;                               // E

  k_cvtw2<<<dim3(16, 2, LL), 256, 0, stream>>>(W_fc, W_res, W2t);
  k_cvtwn<<<dim3(2, 8, LL), 256, 0, stream>>>(W_nrm, Wnt);
  k_cvtx<<<(NPAD*128)/256, 256, 0, stream>>>(features, xb);
  k_zero<<<(NN+255)/256, 256, 0, stream>>>(cursor, NN);
  k_hist<<<(EE+255)/256, 256, 0, stream>>>(dst, cursor);
  k_scan<<<1, 1024, 0, stream>>>(cursor, row_ptr, cursor);
  k_fill<<<(EE+255)/256, 256, 0, stream>>>(src, dst, cursor, csr_src);

  for (int l=0; l<LL; ++l){
    const unsigned short* W2l = W2t + (size_t)l*1024*128;
    const unsigned short* Wnl = Wnt + (size_t)l*128*512;
    const float* al = attn_l + (size_t)l*HH*DD;
    const float* ar = attn_r + (size_t)l*HH*DD;
    const float* bg = b_gat  + (size_t)l*HDIM;
    const float* bn = b_nrm  + (size_t)l*DD;
    const float* lg = ln_g   + (size_t)l*DD;
    const float* lb = ln_b   + (size_t)l*DD;

    k_gemm1m<<<dim3(NPAD/128, 2), 256, 0, stream>>>(xb, W2l, al, ar, featQ, hbuf, elsc, er);
    k_agg<<<NN/4, 256, 0, stream>>>(featQ, hbuf, elsc, er, row_ptr, csr_src, bg);
    k_gemm3m<<<NPAD/128, 256, 0, stream>>>(hbuf, Wnl, bn, lg, lb, out, xb, (l==LL-1) ? 1 : 0);
  }
}

// Round 13
// 784.771 us; speedup vs baseline: 1.1457x; 1.1457x over previous
//
#include <hip/hip_runtime.h>
#include <math.h>

#define NN 50000
#define NPAD 50048            // 391 * 128
#define EE 800000
#define HH 4
#define DD 128
#define HDIM 512
#define LL 4
#define NB 196                // scan blocks: 196*256 = 50176 >= NN

typedef __attribute__((ext_vector_type(8))) short short8;
typedef __attribute__((ext_vector_type(4))) float f32x4;

__device__ __forceinline__ float lk(float x, float s){ return x > 0.f ? x : s*x; }
__device__ __forceinline__ unsigned short f2bf(float f){
  unsigned u = __float_as_uint(f);
  u += 0x7FFFu + ((u >> 16) & 1u);
  return (unsigned short)(u >> 16);
}
__device__ __forceinline__ float lo16(unsigned u){ return __uint_as_float(u << 16); }
__device__ __forceinline__ float hi16(unsigned u){ return __uint_as_float(u & 0xFFFF0000u); }

// ---------------- CSR build (multi-block 3-phase scan) ------------------------------------------
__global__ void k_zero(int* p, int n){ int i = blockIdx.x*blockDim.x+threadIdx.x; if(i<n) p[i]=0; }

__global__ void k_hist(const int* __restrict__ dst, int* __restrict__ cnt){
  int e = blockIdx.x*blockDim.x+threadIdx.x;
  if (e < EE) atomicAdd(&cnt[dst[e]], 1);
}

// phase B: per-block sum of 256 counts
__global__ __launch_bounds__(256) void k_bsum(const int* __restrict__ cnt, int* __restrict__ bsum){
  int t = threadIdx.x;
  int i = blockIdx.x*256 + t;
  int v = (i < NN) ? cnt[i] : 0;
  #pragma unroll
  for (int off=32; off>0; off>>=1) v += __shfl_down(v, off);
  __shared__ int ws[4];
  if ((t & 63) == 0) ws[t>>6] = v;
  __syncthreads();
  if (t == 0) bsum[blockIdx.x] = ws[0]+ws[1]+ws[2]+ws[3];
}

// phase C: single block scans NB block sums -> exclusive boff; writes row_ptr[NN]=total
__global__ __launch_bounds__(256) void k_bscan(const int* __restrict__ bsum,
                                               int* __restrict__ boff,
                                               int* __restrict__ row_ptr){
  __shared__ int part[256];
  int t = threadIdx.x;
  int v = (t < NB) ? bsum[t] : 0;
  part[t] = v;
  __syncthreads();
  for (int off=1; off<256; off<<=1){
    int u = (t>=off) ? part[t-off] : 0;
    __syncthreads();
    part[t] += u;
    __syncthreads();
  }
  if (t < NB) boff[t] = part[t] - v;             // exclusive
  if (t == 255) row_ptr[NN] = part[255];
}

// phase D: per-block exclusive scan + block offset; writes row_ptr AND cursor
__global__ __launch_bounds__(256) void k_bfinal(const int* __restrict__ cnt,
                                                const int* __restrict__ boff,
                                                int* __restrict__ row_ptr,
                                                int* __restrict__ cursor){
  __shared__ int part[256];
  int t = threadIdx.x;
  int i = blockIdx.x*256 + t;
  int v = (i < NN) ? cnt[i] : 0;
  part[t] = v;
  __syncthreads();
  for (int off=1; off<256; off<<=1){
    int u = (t>=off) ? part[t-off] : 0;
    __syncthreads();
    part[t] += u;
    __syncthreads();
  }
  if (i < NN){
    int p = boff[blockIdx.x] + part[t] - v;      // exclusive prefix
    row_ptr[i] = p;
    cursor[i]  = p;
  }
}

__global__ void k_fill(const int* __restrict__ src, const int* __restrict__ dst,
                       int* __restrict__ cursor, int* __restrict__ csr_src){
  int e = blockIdx.x*blockDim.x+threadIdx.x;
  if (e >= EE) return;
  int d = dst[e];
  int p = atomicAdd(&cursor[d], 1);
  csr_src[p] = src[e];
}

// ---------------- weight transposes via LDS tiles (coalesced both sides) -----------------------
__global__ __launch_bounds__(256) void k_cvtw2(const float* __restrict__ Wf,
                                               const float* __restrict__ Wr,
                                               unsigned short* __restrict__ W2t){
  __shared__ float tile[64][65];
  int t = threadIdx.x;
  int n0 = blockIdx.x*64, k0 = blockIdx.y*64, l = blockIdx.z;
  const float* srcp = (n0 < 512) ? Wf : Wr;
  int nsrc = (n0 < 512) ? n0 : (n0 - 512);
  #pragma unroll
  for (int j=0;j<16;++j){
    int idx = t + j*256; int kk = idx>>6, nn = idx&63;
    tile[kk][nn] = srcp[(size_t)(l*128 + k0+kk)*512 + nsrc+nn];
  }
  __syncthreads();
  #pragma unroll
  for (int j=0;j<16;++j){
    int idx = t + j*256; int nn = idx>>6, kk = idx&63;
    W2t[((size_t)l*1024 + n0+nn)*128 + k0+kk] = f2bf(tile[kk][nn]);
  }
}
__global__ __launch_bounds__(256) void k_cvtwn(const float* __restrict__ Wn,
                                               unsigned short* __restrict__ Wnt){
  __shared__ float tile[64][65];
  int t = threadIdx.x;
  int n0 = blockIdx.x*64, k0 = blockIdx.y*64, l = blockIdx.z;
  #pragma unroll
  for (int j=0;j<16;++j){
    int idx = t + j*256; int kk = idx>>6, nn = idx&63;
    tile[kk][nn] = Wn[(size_t)(l*512 + k0+kk)*128 + n0+nn];
  }
  __syncthreads();
  #pragma unroll
  for (int j=0;j<16;++j){
    int idx = t + j*256; int nn = idx>>6, kk = idx&63;
    Wnt[((size_t)l*128 + n0+nn)*512 + k0+kk] = f2bf(tile[kk][nn]);
  }
}
__global__ void k_cvtx(const float* __restrict__ x, unsigned short* __restrict__ xb){
  int idx = blockIdx.x*blockDim.x + threadIdx.x;
  int row = idx >> 7;
  xb[idx] = (row < NN) ? f2bf(x[idx]) : (unsigned short)0;
}

// ---------------- GEMM1 (MFMA): A fragments register-cached, nb-loop over 4 N-tiles ------------
__global__ __launch_bounds__(256) void k_gemm1m(const unsigned short* __restrict__ xb,
                                                const unsigned short* __restrict__ W2t,
                                                const float* __restrict__ al,
                                                const float* __restrict__ ar,
                                                unsigned char* __restrict__ featQ,
                                                unsigned short* __restrict__ hbuf,
                                                float2* __restrict__ elsc,
                                                float* __restrict__ erp){
  __shared__ __attribute__((aligned(16))) unsigned short sA[128*136];
  __shared__ __attribute__((aligned(16))) unsigned short sB[128*136];
  __shared__ float sAl[512], sAr[512], sInv[128];
  int t = threadIdx.x;
  int m0 = blockIdx.x*128;
  int isRes = blockIdx.y;                        // 0 feat / 1 res
  if (!isRes){
    sAl[t] = al[t]; sAl[256+t] = al[256+t];
    sAr[t] = ar[t]; sAr[256+t] = ar[256+t];
  }
  #pragma unroll
  for (int j=0;j<8;++j){
    int c = t + j*256; int r = c>>4, kc = c&15;
    uint4 v = *(const uint4*)(xb + (size_t)(m0+r)*128 + kc*8);
    *(uint4*)(sA + r*136 + kc*8) = v;
  }
  __syncthreads();

  int lane = t & 63, w = t >> 6;
  int wm = (w & 1)*64, wn = (w >> 1)*64;
  int lrow = lane & 15, quad = lane >> 4;

  short8 af[4][4];                               // [kq][mt]
  #pragma unroll
  for (int kq=0;kq<4;++kq){
    int kb = kq*32 + quad*8;
    #pragma unroll
    for (int mt=0;mt<4;++mt) af[kq][mt] = *(const short8*)(sA + (wm+mt*16+lrow)*136 + kb);
  }

  for (int nb=0; nb<4; ++nb){
    int n0 = isRes*512 + nb*128;
    if (nb) __syncthreads();
    #pragma unroll
    for (int j=0;j<8;++j){
      int c = t + j*256; int r = c>>4, kc = c&15;
      uint4 v = *(const uint4*)(W2t + (size_t)(n0+r)*128 + kc*8);
      *(uint4*)(sB + r*136 + kc*8) = v;
    }
    __syncthreads();

    f32x4 acc[4][4];
    #pragma unroll
    for (int mt=0;mt<4;++mt)
      #pragma unroll
      for (int nt=0;nt<4;++nt) acc[mt][nt] = (f32x4){0.f,0.f,0.f,0.f};

    #pragma unroll
    for (int kq=0;kq<4;++kq){
      int kb = kq*32 + quad*8;
      short8 bf[4];
      #pragma unroll
      for (int nt=0;nt<4;++nt) bf[nt] = *(const short8*)(sB + (wn+nt*16+lrow)*136 + kb);
      #pragma unroll
      for (int mt=0;mt<4;++mt)
        #pragma unroll
        for (int nt=0;nt<4;++nt)
          acc[mt][nt] = __builtin_amdgcn_mfma_f32_16x16x32_bf16(af[kq][mt], bf[nt], acc[mt][nt], 0,0,0);
    }

    __syncthreads();
    #pragma unroll
    for (int mt=0;mt<4;++mt)
      #pragma unroll
      for (int nt=0;nt<4;++nt)
        #pragma unroll
        for (int r=0;r<4;++r)
          sB[(wm+mt*16+quad*4+r)*136 + wn+nt*16+lrow] = f2bf(acc[mt][nt][r]);
    __syncthreads();

    if (isRes){
      #pragma unroll
      for (int j=0;j<8;++j){
        int c = t + j*256; int r = c>>4, kc = c&15;
        uint4 v = *(const uint4*)(sB + r*136 + kc*8);
        *(uint4*)(hbuf + (size_t)(m0+r)*512 + nb*128 + kc*8) = v;
      }
    } else {
      int r = t >> 1, half = t & 1;
      int base = half*64;
      float accl = 0.f, accr = 0.f, amax = 0.f;
      #pragma unroll
      for (int d=0; d<64; d+=4){
        uint2 u = *(const uint2*)&sB[r*136 + base + d];
        float f0=lo16(u.x), f1=hi16(u.x), f2=lo16(u.y), f3=hi16(u.y);
        float4 a  = *(const float4*)&sAl[nb*128 + base + d];
        float4 rr = *(const float4*)&sAr[nb*128 + base + d];
        accl += f0*a.x + f1*a.y + f2*a.z + f3*a.w;
        accr += f0*rr.x + f1*rr.y + f2*rr.z + f3*rr.w;
        amax = fmaxf(amax, fmaxf(fmaxf(fabsf(f0), fabsf(f1)), fmaxf(fabsf(f2), fabsf(f3))));
      }
      accl += __shfl_xor(accl, 1);
      accr += __shfl_xor(accr, 1);
      amax = fmaxf(amax, __shfl_xor(amax, 1));
      float am = fmaxf(amax, 1e-8f);
      if (half == 0){
        sInv[r] = 127.f / am;
        if ((m0+r) < NN){
          elsc[(size_t)(m0+r)*4 + nb] = make_float2(accl, am * (1.f/127.f));
          erp[(size_t)(m0+r)*4 + nb] = accr;
        }
      }
      __syncthreads();
      float qinv = sInv[r];
      unsigned char* qdst = featQ + (size_t)(m0+r)*512 + nb*128 + base;
      #pragma unroll
      for (int g=0; g<4; ++g){
        uint4 ua = *(const uint4*)&sB[r*136 + base + g*16];
        uint4 ub = *(const uint4*)&sB[r*136 + base + g*16 + 8];
        unsigned vals[8] = {ua.x, ua.y, ua.z, ua.w, ub.x, ub.y, ub.z, ub.w};
        unsigned p[4];
        #pragma unroll
        for (int j=0;j<4;++j){
          unsigned vlo = vals[2*j], vhi = vals[2*j+1];
          int q0 = (int)rintf(lo16(vlo)*qinv) + 128;
          int q1 = (int)rintf(hi16(vlo)*qinv) + 128;
          int q2 = (int)rintf(lo16(vhi)*qinv) + 128;
          int q3 = (int)rintf(hi16(vhi)*qinv) + 128;
          p[j] = (unsigned)q0 | ((unsigned)q1<<8) | ((unsigned)q2<<16) | ((unsigned)q3<<24);
        }
        *(uint4*)(qdst + g*16) = make_uint4(p[0],p[1],p[2],p[3]);
      }
    }
  }
}

// ---------------- edge softmax + aggregation: int8 gather, single pass, 4x unroll --------------
__global__ __launch_bounds__(256) void k_agg(const unsigned char* __restrict__ featQ,
                                             unsigned short* __restrict__ hbuf,
                                             const float2* __restrict__ elsc,
                                             const float* __restrict__ er,
                                             const int* __restrict__ row_ptr,
                                             const int* __restrict__ csr_src,
                                             const float* __restrict__ b_gat){
  int t = threadIdx.x;
  int lane = t & 63;
  int node = blockIdx.x*4 + (t>>6);              // NN % 4 == 0, grid exact
  int beg = row_ptr[node], end = row_ptr[node+1];
  int hd = lane >> 4;
  float erh = er[(size_t)node*4 + hd];

  float z = 0.f, sws = 0.f;
  float a0=0.f,a1=0.f,a2=0.f,a3=0.f,a4=0.f,a5=0.f,a6=0.f,a7=0.f;
  const uint2* fQ = (const uint2*)featQ;         // row = 64 uint2 (512 bytes)

  int i = beg;
  for (; i + 3 < end; i += 4){
    int s0 = csr_src[i], s1 = csr_src[i+1], s2 = csr_src[i+2], s3 = csr_src[i+3];
    float2 q0 = elsc[(size_t)s0*4 + hd];
    float2 q1 = elsc[(size_t)s1*4 + hd];
    float2 q2 = elsc[(size_t)s2*4 + hd];
    float2 q3 = elsc[(size_t)s3*4 + hd];
    uint2 f0 = fQ[(size_t)s0*64 + lane];
    uint2 f1 = fQ[(size_t)s1*64 + lane];
    uint2 f2 = fQ[(size_t)s2*64 + lane];
    uint2 f3 = fQ[(size_t)s3*64 + lane];
    float w0 = __expf(lk(q0.x + erh, 0.2f));
    float w1 = __expf(lk(q1.x + erh, 0.2f));
    float w2 = __expf(lk(q2.x + erh, 0.2f));
    float w3 = __expf(lk(q3.x + erh, 0.2f));
    float ws0 = w0*q0.y, ws1 = w1*q1.y, ws2 = w2*q2.y, ws3 = w3*q3.y;
    z += w0 + w1 + w2 + w3;
    sws += ws0 + ws1 + ws2 + ws3;
    a0 += ws0*(float)(f0.x & 255u)      + ws1*(float)(f1.x & 255u)      + ws2*(float)(f2.x & 255u)      + ws3*(float)(f3.x & 255u);
    a1 += ws0*(float)((f0.x>>8) & 255u) + ws1*(float)((f1.x>>8) & 255u) + ws2*(float)((f2.x>>8) & 255u) + ws3*(float)((f3.x>>8) & 255u);
    a2 += ws0*(float)((f0.x>>16)& 255u) + ws1*(float)((f1.x>>16)& 255u) + ws2*(float)((f2.x>>16)& 255u) + ws3*(float)((f3.x>>16)& 255u);
    a3 += ws0*(float)(f0.x>>24)         + ws1*(float)(f1.x>>24)         + ws2*(float)(f2.x>>24)         + ws3*(float)(f3.x>>24);
    a4 += ws0*(float)(f0.y & 255u)      + ws1*(float)(f1.y & 255u)      + ws2*(float)(f2.y & 255u)      + ws3*(float)(f3.y & 255u);
    a5 += ws0*(float)((f0.y>>8) & 255u) + ws1*(float)((f1.y>>8) & 255u) + ws2*(float)((f2.y>>8) & 255u) + ws3*(float)((f3.y>>8) & 255u);
    a6 += ws0*(float)((f0.y>>16)& 255u) + ws1*(float)((f1.y>>16)& 255u) + ws2*(float)((f2.y>>16)& 255u) + ws3*(float)((f3.y>>16)& 255u);
    a7 += ws0*(float)(f0.y>>24)         + ws1*(float)(f1.y>>24)         + ws2*(float)(f2.y>>24)         + ws3*(float)(f3.y>>24);
  }
  for (; i < end; ++i){
    int s = csr_src[i];
    float2 q = elsc[(size_t)s*4 + hd];
    uint2 f = fQ[(size_t)s*64 + lane];
    float w = __expf(lk(q.x + erh, 0.2f));
    float ws = w*q.y;
    z += w; sws += ws;
    a0 += ws*(float)(f.x & 255u);       a1 += ws*(float)((f.x>>8) & 255u);
    a2 += ws*(float)((f.x>>16) & 255u); a3 += ws*(float)(f.x>>24);
    a4 += ws*(float)(f.y & 255u);       a5 += ws*(float)((f.y>>8) & 255u);
    a6 += ws*(float)((f.y>>16) & 255u); a7 += ws*(float)(f.y>>24);
  }
  float iz = 1.f / fmaxf(z, 1e-20f);
  float off = 128.f * sws;

  uint4* rp = (uint4*)(hbuf + (size_t)node*HDIM) + lane;
  uint4 rv = *rp;
  const float4* bp = (const float4*)b_gat;
  float4 b1 = bp[2*lane], b2 = bp[2*lane+1];
  float o0 = lk((a0-off)*iz + lo16(rv.x) + b1.x, 0.01f);
  float o1 = lk((a1-off)*iz + hi16(rv.x) + b1.y, 0.01f);
  float o2 = lk((a2-off)*iz + lo16(rv.y) + b1.z, 0.01f);
  float o3 = lk((a3-off)*iz + hi16(rv.y) + b1.w, 0.01f);
  float o4 = lk((a4-off)*iz + lo16(rv.z) + b2.x, 0.01f);
  float o5 = lk((a5-off)*iz + hi16(rv.z) + b2.y, 0.01f);
  float o6 = lk((a6-off)*iz + lo16(rv.w) + b2.z, 0.01f);
  float o7 = lk((a7-off)*iz + hi16(rv.w) + b2.w, 0.01f);
  uint4 wv;
  wv.x = (unsigned)f2bf(o0) | ((unsigned)f2bf(o1) << 16);
  wv.y = (unsigned)f2bf(o2) | ((unsigned)f2bf(o3) << 16);
  wv.z = (unsigned)f2bf(o4) | ((unsigned)f2bf(o5) << 16);
  wv.w = (unsigned)f2bf(o6) | ((unsigned)f2bf(o7) << 16);
  *rp = wv;
}

// ---------------- GEMM3 (MFMA, K=512) + LayerNorm; A and B both LDS-staged ---------------------
__global__ __launch_bounds__(256) void k_gemm3m(const unsigned short* __restrict__ h,
                                                const unsigned short* __restrict__ Wnt,
                                                const float* __restrict__ bn,
                                                const float* __restrict__ lng,
                                                const float* __restrict__ lnb,
                                                float* __restrict__ out,
                                                unsigned short* __restrict__ xb,
                                                int writeOut){
  __shared__ __attribute__((aligned(16))) char smem[2*128*136*2];
  unsigned short* sA = (unsigned short*)smem;
  unsigned short* sB = sA + 128*136;
  float* yf = (float*)smem;
  int t = threadIdx.x;
  int m0 = blockIdx.x*128;
  int lane = t & 63, w = t >> 6;
  int wm = (w & 1)*64, wn = (w >> 1)*64;
  int lrow = lane & 15, quad = lane >> 4;

  f32x4 acc[4][4];
  #pragma unroll
  for (int mt=0;mt<4;++mt)
    #pragma unroll
    for (int nt=0;nt<4;++nt) acc[mt][nt] = (f32x4){0.f,0.f,0.f,0.f};

  for (int kc2=0; kc2<4; ++kc2){
    if (kc2) __syncthreads();
    #pragma unroll
    for (int j=0;j<8;++j){
      int c = t + j*256; int r = c>>4, kc = c&15;
      uint4 v = *(const uint4*)(h + (size_t)(m0+r)*512 + kc2*128 + kc*8);
      *(uint4*)(sA + r*136 + kc*8) = v;
    }
    #pragma unroll
    for (int j=0;j<8;++j){
      int c = t + j*256; int r = c>>4, kc = c&15;
      uint4 v = *(const uint4*)(Wnt + (size_t)r*512 + kc2*128 + kc*8);
      *(uint4*)(sB + r*136 + kc*8) = v;
    }
    __syncthreads();
    #pragma unroll
    for (int kq=0;kq<4;++kq){
      int kb = kq*32 + quad*8;
      short8 af[4], bf[4];
      #pragma unroll
      for (int mt=0;mt<4;++mt) af[mt] = *(const short8*)(sA + (wm+mt*16+lrow)*136 + kb);
      #pragma unroll
      for (int nt=0;nt<4;++nt) bf[nt] = *(const short8*)(sB + (wn+nt*16+lrow)*136 + kb);
      #pragma unroll
      for (int mt=0;mt<4;++mt)
        #pragma unroll
        for (int nt=0;nt<4;++nt)
          acc[mt][nt] = __builtin_amdgcn_mfma_f32_16x16x32_bf16(af[mt], bf[nt], acc[mt][nt], 0,0,0);
    }
  }

  float bnv[4];
  #pragma unroll
  for (int nt=0;nt<4;++nt) bnv[nt] = bn[wn + nt*16 + lrow];
  __syncthreads();
  #pragma unroll
  for (int mt=0;mt<4;++mt)
    #pragma unroll
    for (int nt=0;nt<4;++nt)
      #pragma unroll
      for (int r=0;r<4;++r)
        yf[(wm+mt*16+quad*4+r)*132 + wn+nt*16+lrow] = acc[mt][nt][r] + bnv[nt];
  __syncthreads();

  float g0 = lng[lane], g1 = lng[64+lane];
  float bb0 = lnb[lane], bb1 = lnb[64+lane];
  for (int rr = w*32; rr < w*32+32; ++rr){
    float v0 = yf[rr*132 + lane], v1 = yf[rr*132 + 64 + lane];
    float s = v0 + v1;
    #pragma unroll
    for (int off=32; off>0; off>>=1) s += __shfl_xor(s, off);
    float mu = s * (1.f/128.f);
    float d0 = v0-mu, d1 = v1-mu;
    float q = d0*d0 + d1*d1;
    #pragma unroll
    for (int off=32; off>0; off>>=1) q += __shfl_xor(q, off);
    float inv = rsqrtf(q*(1.f/128.f) + 1e-5f);
    int grow = m0 + rr;
    if (grow < NN){
      float o0 = d0*inv*g0 + bb0;
      float o1 = d1*inv*g1 + bb1;
      xb[(size_t)grow*128 + lane]      = f2bf(o0);
      xb[(size_t)grow*128 + 64 + lane] = f2bf(o1);
      if (writeOut){
        out[(size_t)grow*128 + lane]      = o0;
        out[(size_t)grow*128 + 64 + lane] = o1;
      }
    }
  }
}

extern "C" void kernel_launch(void* const* d_in, const int* in_sizes, int n_in,
                              void* d_out, int out_size, void* d_ws, size_t ws_size,
                              hipStream_t stream){
  const float* features = (const float*)d_in[0];
  const int*   src      = (const int*)d_in[1];
  const int*   dst      = (const int*)d_in[2];
  const float* W_fc     = (const float*)d_in[3];
  const float* attn_l   = (const float*)d_in[4];
  const float* attn_r   = (const float*)d_in[5];
  const float* W_res    = (const float*)d_in[6];
  const float* b_gat    = (const float*)d_in[7];
  const float* W_nrm    = (const float*)d_in[8];
  const float* b_nrm    = (const float*)d_in[9];
  const float* ln_g     = (const float*)d_in[10];
  const float* ln_b     = (const float*)d_in[11];
  float* out = (float*)d_out;

  // workspace (~97 MB)
  unsigned short* xb    = (unsigned short*)d_ws;            // [NPAD,128] bf16
  unsigned short* hbuf  = xb + (size_t)NPAD*128;            // [NPAD,512] bf16 (res -> h)
  unsigned short* W2t   = hbuf + (size_t)NPAD*512;          // [L,1024,128] bf16
  unsigned short* Wnt   = W2t + (size_t)LL*1024*128;        // [L,128,512] bf16
  unsigned char* featQ  = (unsigned char*)(Wnt + (size_t)LL*128*512);  // [NPAD,512] u8
  float2* elsc = (float2*)(featQ + (size_t)NPAD*512);       // [N,4] {el, scale}
  float* er = (float*)(elsc + (size_t)NN*4);                // [N,4]
  int* row_ptr = (int*)(er + (size_t)NN*4);                 // N+1
  int* cursor  = row_ptr + (NN+1);                          // N
  int* csr_src = cursor + NN;                               // E
  int* cnt     = csr_src + EE;                              // N
  int* bsum    = cnt + NN;                                  // NB
  int* boff    = bsum + NB;                                 // NB

  k_cvtw2<<<dim3(16, 2, LL), 256, 0, stream>>>(W_fc, W_res, W2t);
  k_cvtwn<<<dim3(2, 8, LL), 256, 0, stream>>>(W_nrm, Wnt);
  k_cvtx<<<(NPAD*128)/256, 256, 0, stream>>>(features, xb);
  k_zero<<<(NN+255)/256, 256, 0, stream>>>(cnt, NN);
  k_hist<<<(EE+255)/256, 256, 0, stream>>>(dst, cnt);
  k_bsum<<<NB, 256, 0, stream>>>(cnt, bsum);
  k_bscan<<<1, 256, 0, stream>>>(bsum, boff, row_ptr);
  k_bfinal<<<NB, 256, 0, stream>>>(cnt, boff, row_ptr, cursor);
  k_fill<<<(EE+255)/256, 256, 0, stream>>>(src, dst, cursor, csr_src);

  for (int l=0; l<LL; ++l){
    const unsigned short* W2l = W2t + (size_t)l*1024*128;
    const unsigned short* Wnl = Wnt + (size_t)l*128*512;
    const float* al = attn_l + (size_t)l*HH*DD;
    const float* ar = attn_r + (size_t)l*HH*DD;
    const float* bg = b_gat  + (size_t)l*HDIM;
    const float* bn = b_nrm  + (size_t)l*DD;
    const float* lg = ln_g   + (size_t)l*DD;
    const float* lb = ln_b   + (size_t)l*DD;

    k_gemm1m<<<dim3(NPAD/128, 2), 256, 0, stream>>>(xb, W2l, al, ar, featQ, hbuf, elsc, er);
    k_agg<<<NN/4, 256, 0, stream>>>(featQ, hbuf, elsc, er, row_ptr, csr_src, bg);
    k_gemm3m<<<NPAD/128, 256, 0, stream>>>(hbuf, Wnl, bn, lg, lb, out, xb, (l==LL-1) ? 1 : 0);
  }
}

// Round 14
// 767.567 us; speedup vs baseline: 1.1714x; 1.0224x over previous
//
#include <hip/hip_runtime.h>
#include <math.h>

#define NN 50000
#define NPAD 50048            // 391 * 128
#define EE 800000
#define HH 4
#define DD 128
#define HDIM 512
#define LL 4
#define NB 196                // scan blocks: 196*256 = 50176 >= NN

typedef __attribute__((ext_vector_type(8))) short short8;
typedef __attribute__((ext_vector_type(4))) float f32x4;

__device__ __forceinline__ float lk(float x, float s){ return x > 0.f ? x : s*x; }
__device__ __forceinline__ unsigned short f2bf(float f){
  unsigned u = __float_as_uint(f);
  u += 0x7FFFu + ((u >> 16) & 1u);
  return (unsigned short)(u >> 16);
}
__device__ __forceinline__ float lo16(unsigned u){ return __uint_as_float(u << 16); }
__device__ __forceinline__ float hi16(unsigned u){ return __uint_as_float(u & 0xFFFF0000u); }
__device__ __forceinline__ float bf2f(unsigned short u){ return __uint_as_float(((unsigned)u) << 16); }

// ---------------- CSR build (multi-block 3-phase scan) ------------------------------------------
__global__ void k_zero(int* p, int n){ int i = blockIdx.x*blockDim.x+threadIdx.x; if(i<n) p[i]=0; }

__global__ void k_hist(const int* __restrict__ dst, int* __restrict__ cnt){
  int e = blockIdx.x*blockDim.x+threadIdx.x;
  if (e < EE) atomicAdd(&cnt[dst[e]], 1);
}

__global__ __launch_bounds__(256) void k_bsum(const int* __restrict__ cnt, int* __restrict__ bsum){
  int t = threadIdx.x;
  int i = blockIdx.x*256 + t;
  int v = (i < NN) ? cnt[i] : 0;
  #pragma unroll
  for (int off=32; off>0; off>>=1) v += __shfl_down(v, off);
  __shared__ int ws[4];
  if ((t & 63) == 0) ws[t>>6] = v;
  __syncthreads();
  if (t == 0) bsum[blockIdx.x] = ws[0]+ws[1]+ws[2]+ws[3];
}

__global__ __launch_bounds__(256) void k_bscan(const int* __restrict__ bsum,
                                               int* __restrict__ boff,
                                               int* __restrict__ row_ptr){
  __shared__ int part[256];
  int t = threadIdx.x;
  int v = (t < NB) ? bsum[t] : 0;
  part[t] = v;
  __syncthreads();
  for (int off=1; off<256; off<<=1){
    int u = (t>=off) ? part[t-off] : 0;
    __syncthreads();
    part[t] += u;
    __syncthreads();
  }
  if (t < NB) boff[t] = part[t] - v;
  if (t == 255) row_ptr[NN] = part[255];
}

__global__ __launch_bounds__(256) void k_bfinal(const int* __restrict__ cnt,
                                                const int* __restrict__ boff,
                                                int* __restrict__ row_ptr,
                                                int* __restrict__ cursor){
  __shared__ int part[256];
  int t = threadIdx.x;
  int i = blockIdx.x*256 + t;
  int v = (i < NN) ? cnt[i] : 0;
  part[t] = v;
  __syncthreads();
  for (int off=1; off<256; off<<=1){
    int u = (t>=off) ? part[t-off] : 0;
    __syncthreads();
    part[t] += u;
    __syncthreads();
  }
  if (i < NN){
    int p = boff[blockIdx.x] + part[t] - v;
    row_ptr[i] = p;
    cursor[i]  = p;
  }
}

__global__ void k_fill(const int* __restrict__ src, const int* __restrict__ dst,
                       int* __restrict__ cursor, int* __restrict__ csr_src){
  int e = blockIdx.x*blockDim.x+threadIdx.x;
  if (e >= EE) return;
  int d = dst[e];
  int p = atomicAdd(&cursor[d], 1);
  csr_src[p] = src[e];
}

// ---------------- weight transposes via LDS tiles (coalesced both sides) -----------------------
__global__ __launch_bounds__(256) void k_cvtw2(const float* __restrict__ Wf,
                                               const float* __restrict__ Wr,
                                               unsigned short* __restrict__ W2t){
  __shared__ float tile[64][65];
  int t = threadIdx.x;
  int n0 = blockIdx.x*64, k0 = blockIdx.y*64, l = blockIdx.z;
  const float* srcp = (n0 < 512) ? Wf : Wr;
  int nsrc = (n0 < 512) ? n0 : (n0 - 512);
  #pragma unroll
  for (int j=0;j<16;++j){
    int idx = t + j*256; int kk = idx>>6, nn = idx&63;
    tile[kk][nn] = srcp[(size_t)(l*128 + k0+kk)*512 + nsrc+nn];
  }
  __syncthreads();
  #pragma unroll
  for (int j=0;j<16;++j){
    int idx = t + j*256; int nn = idx>>6, kk = idx&63;
    W2t[((size_t)l*1024 + n0+nn)*128 + k0+kk] = f2bf(tile[kk][nn]);
  }
}
__global__ __launch_bounds__(256) void k_cvtwn(const float* __restrict__ Wn,
                                               unsigned short* __restrict__ Wnt){
  __shared__ float tile[64][65];
  int t = threadIdx.x;
  int n0 = blockIdx.x*64, k0 = blockIdx.y*64, l = blockIdx.z;
  #pragma unroll
  for (int j=0;j<16;++j){
    int idx = t + j*256; int kk = idx>>6, nn = idx&63;
    tile[kk][nn] = Wn[(size_t)(l*512 + k0+kk)*128 + n0+nn];
  }
  __syncthreads();
  #pragma unroll
  for (int j=0;j<16;++j){
    int idx = t + j*256; int nn = idx>>6, kk = idx&63;
    Wnt[((size_t)l*128 + n0+nn)*512 + k0+kk] = f2bf(tile[kk][nn]);
  }
}
__global__ void k_cvtx(const float* __restrict__ x, unsigned short* __restrict__ xb){
  int idx = blockIdx.x*blockDim.x + threadIdx.x;
  int row = idx >> 7;
  xb[idx] = (row < NN) ? f2bf(x[idx]) : (unsigned short)0;
}

// ---------------- shared epilogue helpers (feat quant / logits) --------------------------------
// epilogue for one 128x128 feat tile sitting in sC (bf16, stride 136); head hd.
__device__ __forceinline__ void feat_epilogue(const unsigned short* sC, float* sInv,
                                              const float* sAl, const float* sAr, int hd,
                                              int m0, int t,
                                              unsigned char* __restrict__ featQ,
                                              float2* __restrict__ elsc,
                                              float* __restrict__ erp){
  int r = t >> 1, half = t & 1;
  int base = half*64;
  float accl = 0.f, accr = 0.f, amax = 0.f;
  #pragma unroll
  for (int d=0; d<64; d+=4){
    uint2 u = *(const uint2*)&sC[r*136 + base + d];
    float f0=lo16(u.x), f1=hi16(u.x), f2=lo16(u.y), f3=hi16(u.y);
    float4 a  = *(const float4*)&sAl[hd*128 + base + d];
    float4 rr = *(const float4*)&sAr[hd*128 + base + d];
    accl += f0*a.x + f1*a.y + f2*a.z + f3*a.w;
    accr += f0*rr.x + f1*rr.y + f2*rr.z + f3*rr.w;
    amax = fmaxf(amax, fmaxf(fmaxf(fabsf(f0), fabsf(f1)), fmaxf(fabsf(f2), fabsf(f3))));
  }
  accl += __shfl_xor(accl, 1);
  accr += __shfl_xor(accr, 1);
  amax = fmaxf(amax, __shfl_xor(amax, 1));
  float am = fmaxf(amax, 1e-8f);
  if (half == 0){
    sInv[r] = 127.f / am;
    if ((m0+r) < NN){
      elsc[(size_t)(m0+r)*4 + hd] = make_float2(accl, am * (1.f/127.f));
      erp[(size_t)(m0+r)*4 + hd] = accr;
    }
  }
  __syncthreads();
  float qinv = sInv[r];
  unsigned char* qdst = featQ + (size_t)(m0+r)*512 + hd*128 + base;
  #pragma unroll
  for (int g=0; g<4; ++g){
    uint4 ua = *(const uint4*)&sC[r*136 + base + g*16];
    uint4 ub = *(const uint4*)&sC[r*136 + base + g*16 + 8];
    unsigned vals[8] = {ua.x, ua.y, ua.z, ua.w, ub.x, ub.y, ub.z, ub.w};
    unsigned p[4];
    #pragma unroll
    for (int j=0;j<4;++j){
      unsigned vlo = vals[2*j], vhi = vals[2*j+1];
      int q0 = (int)rintf(lo16(vlo)*qinv) + 128;
      int q1 = (int)rintf(hi16(vlo)*qinv) + 128;
      int q2 = (int)rintf(lo16(vhi)*qinv) + 128;
      int q3 = (int)rintf(hi16(vhi)*qinv) + 128;
      p[j] = (unsigned)q0 | ((unsigned)q1<<8) | ((unsigned)q2<<16) | ((unsigned)q3<<24);
    }
    *(uint4*)(qdst + g*16) = make_uint4(p[0],p[1],p[2],p[3]);
  }
}

// ---------------- GEMM1 (layer 0 only): A register-cached, nb-loop over 4 N-tiles --------------
__global__ __launch_bounds__(256) void k_gemm1m(const unsigned short* __restrict__ xb,
                                                const unsigned short* __restrict__ W2t,
                                                const float* __restrict__ al,
                                                const float* __restrict__ ar,
                                                unsigned char* __restrict__ featQ,
                                                unsigned short* __restrict__ hbuf,
                                                float2* __restrict__ elsc,
                                                float* __restrict__ erp){
  __shared__ __attribute__((aligned(16))) unsigned short sA[128*136];
  __shared__ __attribute__((aligned(16))) unsigned short sB[128*136];
  __shared__ float sAl[512], sAr[512], sInv[128];
  int t = threadIdx.x;
  int m0 = blockIdx.x*128;
  int isRes = blockIdx.y;
  if (!isRes){
    sAl[t] = al[t]; sAl[256+t] = al[256+t];
    sAr[t] = ar[t]; sAr[256+t] = ar[256+t];
  }
  #pragma unroll
  for (int j=0;j<8;++j){
    int c = t + j*256; int r = c>>4, kc = c&15;
    uint4 v = *(const uint4*)(xb + (size_t)(m0+r)*128 + kc*8);
    *(uint4*)(sA + r*136 + kc*8) = v;
  }
  __syncthreads();

  int lane = t & 63, w = t >> 6;
  int wm = (w & 1)*64, wn = (w >> 1)*64;
  int lrow = lane & 15, quad = lane >> 4;

  short8 af[4][4];
  #pragma unroll
  for (int kq=0;kq<4;++kq){
    int kb = kq*32 + quad*8;
    #pragma unroll
    for (int mt=0;mt<4;++mt) af[kq][mt] = *(const short8*)(sA + (wm+mt*16+lrow)*136 + kb);
  }

  for (int nb=0; nb<4; ++nb){
    int n0 = isRes*512 + nb*128;
    if (nb) __syncthreads();
    #pragma unroll
    for (int j=0;j<8;++j){
      int c = t + j*256; int r = c>>4, kc = c&15;
      uint4 v = *(const uint4*)(W2t + (size_t)(n0+r)*128 + kc*8);
      *(uint4*)(sB + r*136 + kc*8) = v;
    }
    __syncthreads();

    f32x4 acc[4][4];
    #pragma unroll
    for (int mt=0;mt<4;++mt)
      #pragma unroll
      for (int nt=0;nt<4;++nt) acc[mt][nt] = (f32x4){0.f,0.f,0.f,0.f};

    #pragma unroll
    for (int kq=0;kq<4;++kq){
      int kb = kq*32 + quad*8;
      short8 bf[4];
      #pragma unroll
      for (int nt=0;nt<4;++nt) bf[nt] = *(const short8*)(sB + (wn+nt*16+lrow)*136 + kb);
      #pragma unroll
      for (int mt=0;mt<4;++mt)
        #pragma unroll
        for (int nt=0;nt<4;++nt)
          acc[mt][nt] = __builtin_amdgcn_mfma_f32_16x16x32_bf16(af[kq][mt], bf[nt], acc[mt][nt], 0,0,0);
    }

    __syncthreads();
    #pragma unroll
    for (int mt=0;mt<4;++mt)
      #pragma unroll
      for (int nt=0;nt<4;++nt)
        #pragma unroll
        for (int r=0;r<4;++r)
          sB[(wm+mt*16+quad*4+r)*136 + wn+nt*16+lrow] = f2bf(acc[mt][nt][r]);
    __syncthreads();

    if (isRes){
      #pragma unroll
      for (int j=0;j<8;++j){
        int c = t + j*256; int r = c>>4, kc = c&15;
        uint4 v = *(const uint4*)(sB + r*136 + kc*8);
        *(uint4*)(hbuf + (size_t)(m0+r)*512 + nb*128 + kc*8) = v;
      }
    } else {
      feat_epilogue(sB, sInv, sAl, sAr, nb, m0, t, featQ, elsc, erp);
    }
  }
}

// ---------------- edge softmax + aggregation: int8 gather, single pass, 4x unroll --------------
__global__ __launch_bounds__(256) void k_agg(const unsigned char* __restrict__ featQ,
                                             unsigned short* __restrict__ hbuf,
                                             const float2* __restrict__ elsc,
                                             const float* __restrict__ er,
                                             const int* __restrict__ row_ptr,
                                             const int* __restrict__ csr_src,
                                             const float* __restrict__ b_gat){
  int t = threadIdx.x;
  int lane = t & 63;
  int node = blockIdx.x*4 + (t>>6);
  int beg = row_ptr[node], end = row_ptr[node+1];
  int hd = lane >> 4;
  float erh = er[(size_t)node*4 + hd];

  float z = 0.f, sws = 0.f;
  float a0=0.f,a1=0.f,a2=0.f,a3=0.f,a4=0.f,a5=0.f,a6=0.f,a7=0.f;
  const uint2* fQ = (const uint2*)featQ;

  int i = beg;
  for (; i + 3 < end; i += 4){
    int s0 = csr_src[i], s1 = csr_src[i+1], s2 = csr_src[i+2], s3 = csr_src[i+3];
    float2 q0 = elsc[(size_t)s0*4 + hd];
    float2 q1 = elsc[(size_t)s1*4 + hd];
    float2 q2 = elsc[(size_t)s2*4 + hd];
    float2 q3 = elsc[(size_t)s3*4 + hd];
    uint2 f0 = fQ[(size_t)s0*64 + lane];
    uint2 f1 = fQ[(size_t)s1*64 + lane];
    uint2 f2 = fQ[(size_t)s2*64 + lane];
    uint2 f3 = fQ[(size_t)s3*64 + lane];
    float w0 = __expf(lk(q0.x + erh, 0.2f));
    float w1 = __expf(lk(q1.x + erh, 0.2f));
    float w2 = __expf(lk(q2.x + erh, 0.2f));
    float w3 = __expf(lk(q3.x + erh, 0.2f));
    float ws0 = w0*q0.y, ws1 = w1*q1.y, ws2 = w2*q2.y, ws3 = w3*q3.y;
    z += w0 + w1 + w2 + w3;
    sws += ws0 + ws1 + ws2 + ws3;
    a0 += ws0*(float)(f0.x & 255u)      + ws1*(float)(f1.x & 255u)      + ws2*(float)(f2.x & 255u)      + ws3*(float)(f3.x & 255u);
    a1 += ws0*(float)((f0.x>>8) & 255u) + ws1*(float)((f1.x>>8) & 255u) + ws2*(float)((f2.x>>8) & 255u) + ws3*(float)((f3.x>>8) & 255u);
    a2 += ws0*(float)((f0.x>>16)& 255u) + ws1*(float)((f1.x>>16)& 255u) + ws2*(float)((f2.x>>16)& 255u) + ws3*(float)((f3.x>>16)& 255u);
    a3 += ws0*(float)(f0.x>>24)         + ws1*(float)(f1.x>>24)         + ws2*(float)(f2.x>>24)         + ws3*(float)(f3.x>>24);
    a4 += ws0*(float)(f0.y & 255u)      + ws1*(float)(f1.y & 255u)      + ws2*(float)(f2.y & 255u)      + ws3*(float)(f3.y & 255u);
    a5 += ws0*(float)((f0.y>>8) & 255u) + ws1*(float)((f1.y>>8) & 255u) + ws2*(float)((f2.y>>8) & 255u) + ws3*(float)((f3.y>>8) & 255u);
    a6 += ws0*(float)((f0.y>>16)& 255u) + ws1*(float)((f1.y>>16)& 255u) + ws2*(float)((f2.y>>16)& 255u) + ws3*(float)((f3.y>>16)& 255u);
    a7 += ws0*(float)(f0.y>>24)         + ws1*(float)(f1.y>>24)         + ws2*(float)(f2.y>>24)         + ws3*(float)(f3.y>>24);
  }
  for (; i < end; ++i){
    int s = csr_src[i];
    float2 q = elsc[(size_t)s*4 + hd];
    uint2 f = fQ[(size_t)s*64 + lane];
    float w = __expf(lk(q.x + erh, 0.2f));
    float ws = w*q.y;
    z += w; sws += ws;
    a0 += ws*(float)(f.x & 255u);       a1 += ws*(float)((f.x>>8) & 255u);
    a2 += ws*(float)((f.x>>16) & 255u); a3 += ws*(float)(f.x>>24);
    a4 += ws*(float)(f.y & 255u);       a5 += ws*(float)((f.y>>8) & 255u);
    a6 += ws*(float)((f.y>>16) & 255u); a7 += ws*(float)(f.y>>24);
  }
  float iz = 1.f / fmaxf(z, 1e-20f);
  float off = 128.f * sws;

  uint4* rp = (uint4*)(hbuf + (size_t)node*HDIM) + lane;
  uint4 rv = *rp;
  const float4* bp = (const float4*)b_gat;
  float4 b1 = bp[2*lane], b2 = bp[2*lane+1];
  float o0 = lk((a0-off)*iz + lo16(rv.x) + b1.x, 0.01f);
  float o1 = lk((a1-off)*iz + hi16(rv.x) + b1.y, 0.01f);
  float o2 = lk((a2-off)*iz + lo16(rv.y) + b1.z, 0.01f);
  float o3 = lk((a3-off)*iz + hi16(rv.y) + b1.w, 0.01f);
  float o4 = lk((a4-off)*iz + lo16(rv.z) + b2.x, 0.01f);
  float o5 = lk((a5-off)*iz + hi16(rv.z) + b2.y, 0.01f);
  float o6 = lk((a6-off)*iz + lo16(rv.w) + b2.z, 0.01f);
  float o7 = lk((a7-off)*iz + hi16(rv.w) + b2.w, 0.01f);
  uint4 wv;
  wv.x = (unsigned)f2bf(o0) | ((unsigned)f2bf(o1) << 16);
  wv.y = (unsigned)f2bf(o2) | ((unsigned)f2bf(o3) << 16);
  wv.z = (unsigned)f2bf(o4) | ((unsigned)f2bf(o5) << 16);
  wv.w = (unsigned)f2bf(o6) | ((unsigned)f2bf(o7) << 16);
  *rp = wv;
}

// ---------------- FUSED: gemm3(layer l-1) + LN + gemm1(layer l), one block per 128-row tile ----
// hbuf rows m0..m0+127 are read (h of prev layer) then overwritten (res of this layer): safe,
// block-local. y passes through bf16 in sA (in place over dead h tile); LN in-place in sA.
__global__ __launch_bounds__(256) void k_fused(unsigned short* __restrict__ hbuf,
                                               const unsigned short* __restrict__ Wnt,
                                               const float* __restrict__ bn,
                                               const float* __restrict__ lng,
                                               const float* __restrict__ lnb,
                                               const unsigned short* __restrict__ W2t,
                                               const float* __restrict__ al,
                                               const float* __restrict__ ar,
                                               unsigned char* __restrict__ featQ,
                                               float2* __restrict__ elsc,
                                               float* __restrict__ erp){
  __shared__ __attribute__((aligned(16))) unsigned short sA[128*136];
  __shared__ __attribute__((aligned(16))) unsigned short sB[128*136];
  __shared__ float sAl[512], sAr[512], sInv[128];
  int t = threadIdx.x;
  int m0 = blockIdx.x*128;
  sAl[t] = al[t]; sAl[256+t] = al[256+t];
  sAr[t] = ar[t]; sAr[256+t] = ar[256+t];
  int lane = t & 63, w = t >> 6;
  int wm = (w & 1)*64, wn = (w >> 1)*64;
  int lrow = lane & 15, quad = lane >> 4;

  // ---- phase 1: y = h @ Wnt (K=512) ----
  f32x4 acc[4][4];
  #pragma unroll
  for (int mt=0;mt<4;++mt)
    #pragma unroll
    for (int nt=0;nt<4;++nt) acc[mt][nt] = (f32x4){0.f,0.f,0.f,0.f};

  for (int kc2=0; kc2<4; ++kc2){
    if (kc2) __syncthreads();
    #pragma unroll
    for (int j=0;j<8;++j){
      int c = t + j*256; int r = c>>4, kc = c&15;
      uint4 v = *(const uint4*)(hbuf + (size_t)(m0+r)*512 + kc2*128 + kc*8);
      *(uint4*)(sA + r*136 + kc*8) = v;
    }
    #pragma unroll
    for (int j=0;j<8;++j){
      int c = t + j*256; int r = c>>4, kc = c&15;
      uint4 v = *(const uint4*)(Wnt + (size_t)r*512 + kc2*128 + kc*8);
      *(uint4*)(sB + r*136 + kc*8) = v;
    }
    __syncthreads();
    #pragma unroll
    for (int kq=0;kq<4;++kq){
      int kb = kq*32 + quad*8;
      short8 a4[4], b4[4];
      #pragma unroll
      for (int mt=0;mt<4;++mt) a4[mt] = *(const short8*)(sA + (wm+mt*16+lrow)*136 + kb);
      #pragma unroll
      for (int nt=0;nt<4;++nt) b4[nt] = *(const short8*)(sB + (wn+nt*16+lrow)*136 + kb);
      #pragma unroll
      for (int mt=0;mt<4;++mt)
        #pragma unroll
        for (int nt=0;nt<4;++nt)
          acc[mt][nt] = __builtin_amdgcn_mfma_f32_16x16x32_bf16(a4[mt], b4[nt], acc[mt][nt], 0,0,0);
    }
  }

  // ---- phase 2: y(+bias) bf16 in place over dead h tile in sA ----
  float bnv[4];
  #pragma unroll
  for (int nt=0;nt<4;++nt) bnv[nt] = bn[wn + nt*16 + lrow];
  __syncthreads();
  #pragma unroll
  for (int mt=0;mt<4;++mt)
    #pragma unroll
    for (int nt=0;nt<4;++nt)
      #pragma unroll
      for (int r=0;r<4;++r)
        sA[(wm+mt*16+quad*4+r)*136 + wn+nt*16+lrow] = f2bf(acc[mt][nt][r] + bnv[nt]);
  __syncthreads();

  // ---- phase 3: LayerNorm in place (each wave owns 32 rows) ----
  float g0 = lng[lane], g1 = lng[64+lane];
  float bb0 = lnb[lane], bb1 = lnb[64+lane];
  for (int rr = w*32; rr < w*32+32; ++rr){
    float v0 = bf2f(sA[rr*136 + lane]), v1 = bf2f(sA[rr*136 + 64 + lane]);
    float s = v0 + v1;
    #pragma unroll
    for (int off=32; off>0; off>>=1) s += __shfl_xor(s, off);
    float mu = s * (1.f/128.f);
    float d0 = v0-mu, d1 = v1-mu;
    float q = d0*d0 + d1*d1;
    #pragma unroll
    for (int off=32; off>0; off>>=1) q += __shfl_xor(q, off);
    float inv = rsqrtf(q*(1.f/128.f) + 1e-5f);
    sA[rr*136 + lane]      = f2bf(d0*inv*g0 + bb0);
    sA[rr*136 + 64 + lane] = f2bf(d1*inv*g1 + bb1);
  }
  __syncthreads();

  // ---- phase 4: register-cache A fragments of x tile ----
  short8 af[4][4];
  #pragma unroll
  for (int kq=0;kq<4;++kq){
    int kb = kq*32 + quad*8;
    #pragma unroll
    for (int mt=0;mt<4;++mt) af[kq][mt] = *(const short8*)(sA + (wm+mt*16+lrow)*136 + kb);
  }

  // ---- phase 5: gemm1 over 8 N-tiles (0-3 feat, 4-7 res) ----
  for (int nb=0; nb<8; ++nb){
    #pragma unroll
    for (int j=0;j<8;++j){
      int c = t + j*256; int r = c>>4, kc = c&15;
      uint4 v = *(const uint4*)(W2t + (size_t)(nb*128+r)*128 + kc*8);
      *(uint4*)(sB + r*136 + kc*8) = v;
    }
    __syncthreads();

    f32x4 ac2[4][4];
    #pragma unroll
    for (int mt=0;mt<4;++mt)
      #pragma unroll
      for (int nt=0;nt<4;++nt) ac2[mt][nt] = (f32x4){0.f,0.f,0.f,0.f};

    #pragma unroll
    for (int kq=0;kq<4;++kq){
      int kb = kq*32 + quad*8;
      short8 b4[4];
      #pragma unroll
      for (int nt=0;nt<4;++nt) b4[nt] = *(const short8*)(sB + (wn+nt*16+lrow)*136 + kb);
      #pragma unroll
      for (int mt=0;mt<4;++mt)
        #pragma unroll
        for (int nt=0;nt<4;++nt)
          ac2[mt][nt] = __builtin_amdgcn_mfma_f32_16x16x32_bf16(af[kq][mt], b4[nt], ac2[mt][nt], 0,0,0);
    }

    __syncthreads();
    #pragma unroll
    for (int mt=0;mt<4;++mt)
      #pragma unroll
      for (int nt=0;nt<4;++nt)
        #pragma unroll
        for (int r=0;r<4;++r)
          sB[(wm+mt*16+quad*4+r)*136 + wn+nt*16+lrow] = f2bf(ac2[mt][nt][r]);
    __syncthreads();

    if (nb >= 4){
      #pragma unroll
      for (int j=0;j<8;++j){
        int c = t + j*256; int r = c>>4, kc = c&15;
        uint4 v = *(const uint4*)(sB + r*136 + kc*8);
        *(uint4*)(hbuf + (size_t)(m0+r)*512 + (nb-4)*128 + kc*8) = v;
      }
    } else {
      feat_epilogue(sB, sInv, sAl, sAr, nb, m0, t, featQ, elsc, erp);
    }
    __syncthreads();                             // epilogue reads of sB done before restage
  }
}

// ---------------- GEMM3 (final layer) + LayerNorm; writes fp32 out -----------------------------
__global__ __launch_bounds__(256) void k_gemm3m(const unsigned short* __restrict__ h,
                                                const unsigned short* __restrict__ Wnt,
                                                const float* __restrict__ bn,
                                                const float* __restrict__ lng,
                                                const float* __restrict__ lnb,
                                                float* __restrict__ out){
  __shared__ __attribute__((aligned(16))) char smem[2*128*136*2];
  unsigned short* sA = (unsigned short*)smem;
  unsigned short* sB = sA + 128*136;
  float* yf = (float*)smem;
  int t = threadIdx.x;
  int m0 = blockIdx.x*128;
  int lane = t & 63, w = t >> 6;
  int wm = (w & 1)*64, wn = (w >> 1)*64;
  int lrow = lane & 15, quad = lane >> 4;

  f32x4 acc[4][4];
  #pragma unroll
  for (int mt=0;mt<4;++mt)
    #pragma unroll
    for (int nt=0;nt<4;++nt) acc[mt][nt] = (f32x4){0.f,0.f,0.f,0.f};

  for (int kc2=0; kc2<4; ++kc2){
    if (kc2) __syncthreads();
    #pragma unroll
    for (int j=0;j<8;++j){
      int c = t + j*256; int r = c>>4, kc = c&15;
      uint4 v = *(const uint4*)(h + (size_t)(m0+r)*512 + kc2*128 + kc*8);
      *(uint4*)(sA + r*136 + kc*8) = v;
    }
    #pragma unroll
    for (int j=0;j<8;++j){
      int c = t + j*256; int r = c>>4, kc = c&15;
      uint4 v = *(const uint4*)(Wnt + (size_t)r*512 + kc2*128 + kc*8);
      *(uint4*)(sB + r*136 + kc*8) = v;
    }
    __syncthreads();
    #pragma unroll
    for (int kq=0;kq<4;++kq){
      int kb = kq*32 + quad*8;
      short8 a4[4], b4[4];
      #pragma unroll
      for (int mt=0;mt<4;++mt) a4[mt] = *(const short8*)(sA + (wm+mt*16+lrow)*136 + kb);
      #pragma unroll
      for (int nt=0;nt<4;++nt) b4[nt] = *(const short8*)(sB + (wn+nt*16+lrow)*136 + kb);
      #pragma unroll
      for (int mt=0;mt<4;++mt)
        #pragma unroll
        for (int nt=0;nt<4;++nt)
          acc[mt][nt] = __builtin_amdgcn_mfma_f32_16x16x32_bf16(a4[mt], b4[nt], acc[mt][nt], 0,0,0);
    }
  }

  float bnv[4];
  #pragma unroll
  for (int nt=0;nt<4;++nt) bnv[nt] = bn[wn + nt*16 + lrow];
  __syncthreads();
  #pragma unroll
  for (int mt=0;mt<4;++mt)
    #pragma unroll
    for (int nt=0;nt<4;++nt)
      #pragma unroll
      for (int r=0;r<4;++r)
        yf[(wm+mt*16+quad*4+r)*132 + wn+nt*16+lrow] = acc[mt][nt][r] + bnv[nt];
  __syncthreads();

  float g0 = lng[lane], g1 = lng[64+lane];
  float bb0 = lnb[lane], bb1 = lnb[64+lane];
  for (int rr = w*32; rr < w*32+32; ++rr){
    float v0 = yf[rr*132 + lane], v1 = yf[rr*132 + 64 + lane];
    float s = v0 + v1;
    #pragma unroll
    for (int off=32; off>0; off>>=1) s += __shfl_xor(s, off);
    float mu = s * (1.f/128.f);
    float d0 = v0-mu, d1 = v1-mu;
    float q = d0*d0 + d1*d1;
    #pragma unroll
    for (int off=32; off>0; off>>=1) q += __shfl_xor(q, off);
    float inv = rsqrtf(q*(1.f/128.f) + 1e-5f);
    int grow = m0 + rr;
    if (grow < NN){
      out[(size_t)grow*128 + lane]      = d0*inv*g0 + bb0;
      out[(size_t)grow*128 + 64 + lane] = d1*inv*g1 + bb1;
    }
  }
}

extern "C" void kernel_launch(void* const* d_in, const int* in_sizes, int n_in,
                              void* d_out, int out_size, void* d_ws, size_t ws_size,
                              hipStream_t stream){
  const float* features = (const float*)d_in[0];
  const int*   src      = (const int*)d_in[1];
  const int*   dst      = (const int*)d_in[2];
  const float* W_fc     = (const float*)d_in[3];
  const float* attn_l   = (const float*)d_in[4];
  const float* attn_r   = (const float*)d_in[5];
  const float* W_res    = (const float*)d_in[6];
  const float* b_gat    = (const float*)d_in[7];
  const float* W_nrm    = (const float*)d_in[8];
  const float* b_nrm    = (const float*)d_in[9];
  const float* ln_g     = (const float*)d_in[10];
  const float* ln_b     = (const float*)d_in[11];
  float* out = (float*)d_out;

  // workspace (~97 MB)
  unsigned short* xb    = (unsigned short*)d_ws;            // [NPAD,128] bf16 (layer-0 input)
  unsigned short* hbuf  = xb + (size_t)NPAD*128;            // [NPAD,512] bf16 (res -> h)
  unsigned short* W2t   = hbuf + (size_t)NPAD*512;          // [L,1024,128] bf16
  unsigned short* Wnt   = W2t + (size_t)LL*1024*128;        // [L,128,512] bf16
  unsigned char* featQ  = (unsigned char*)(Wnt + (size_t)LL*128*512);  // [NPAD,512] u8
  float2* elsc = (float2*)(featQ + (size_t)NPAD*512);       // [N,4] {el, scale}
  float* er = (float*)(elsc + (size_t)NN*4);                // [N,4]
  int* row_ptr = (int*)(er + (size_t)NN*4);                 // N+1
  int* cursor  = row_ptr + (NN+1);                          // N
  int* csr_src = cursor + NN;                               // E
  int* cnt     = csr_src + EE;                              // N
  int* bsum    = cnt + NN;                                  // NB
  int* boff    = bsum + NB;                                 // NB

  k_cvtw2<<<dim3(16, 2, LL), 256, 0, stream>>>(W_fc, W_res, W2t);
  k_cvtwn<<<dim3(2, 8, LL), 256, 0, stream>>>(W_nrm, Wnt);
  k_cvtx<<<(NPAD*128)/256, 256, 0, stream>>>(features, xb);
  k_zero<<<(NN+255)/256, 256, 0, stream>>>(cnt, NN);
  k_hist<<<(EE+255)/256, 256, 0, stream>>>(dst, cnt);
  k_bsum<<<NB, 256, 0, stream>>>(cnt, bsum);
  k_bscan<<<1, 256, 0, stream>>>(bsum, boff, row_ptr);
  k_bfinal<<<NB, 256, 0, stream>>>(cnt, boff, row_ptr, cursor);
  k_fill<<<(EE+255)/256, 256, 0, stream>>>(src, dst, cursor, csr_src);

  // layer 0: gemm1 from xb
  k_gemm1m<<<dim3(NPAD/128, 2), 256, 0, stream>>>(xb, W2t, attn_l, attn_r, featQ, hbuf, elsc, er);
  k_agg<<<NN/4, 256, 0, stream>>>(featQ, hbuf, elsc, er, row_ptr, csr_src, b_gat);

  // layers 1..3: fused gemm3(l-1)+LN(l-1)+gemm1(l), then agg(l)
  for (int l=1; l<LL; ++l){
    k_fused<<<NPAD/128, 256, 0, stream>>>(hbuf,
        Wnt + (size_t)(l-1)*128*512, b_nrm + (size_t)(l-1)*DD,
        ln_g + (size_t)(l-1)*DD, ln_b + (size_t)(l-1)*DD,
        W2t + (size_t)l*1024*128, attn_l + (size_t)l*HH*DD, attn_r + (size_t)l*HH*DD,
        featQ, elsc, er);
    k_agg<<<NN/4, 256, 0, stream>>>(featQ, hbuf, elsc, er, row_ptr, csr_src,
                                    b_gat + (size_t)l*HDIM);
  }

  // final gemm3 + LN -> out (fp32)
  k_gemm3m<<<NPAD/128, 256, 0, stream>>>(hbuf, Wnt + (size_t)3*128*512,
                                         b_nrm + (size_t)3*DD, ln_g + (size_t)3*DD,
                                         ln_b + (size_t)3*DD, out);
}

// Round 15
// 760.454 us; speedup vs baseline: 1.1823x; 1.0094x over previous
//
#include <hip/hip_runtime.h>
#include <math.h>

#define NN 50000
#define NPAD 50048            // 391 * 128
#define EE 800000
#define HH 4
#define DD 128
#define HDIM 512
#define LL 4
#define NB 196                // scan blocks: 196*256 = 50176 >= NN

typedef __attribute__((ext_vector_type(8))) short short8;
typedef __attribute__((ext_vector_type(4))) float f32x4;
typedef __attribute__((address_space(1))) unsigned int g_u32;
typedef __attribute__((address_space(3))) unsigned int l_u32;

__device__ __forceinline__ float lk(float x, float s){ return x > 0.f ? x : s*x; }
__device__ __forceinline__ unsigned short f2bf(float f){
  unsigned u = __float_as_uint(f);
  u += 0x7FFFu + ((u >> 16) & 1u);
  return (unsigned short)(u >> 16);
}
__device__ __forceinline__ float lo16(unsigned u){ return __uint_as_float(u << 16); }
__device__ __forceinline__ float hi16(unsigned u){ return __uint_as_float(u & 0xFFFF0000u); }
__device__ __forceinline__ float bf2f(unsigned short u){ return __uint_as_float(((unsigned)u) << 16); }

// async global->LDS, 16B per lane; LDS dest = wave-uniform base + lane*16
__device__ __forceinline__ void gl16(const unsigned short* g, unsigned short* l){
  __builtin_amdgcn_global_load_lds((g_u32*)g, (l_u32*)l, 16, 0, 0);
}

// stage a 128x128 bf16 tile with xor-swizzle: LDS slot (r, q) <- global (r, q ^ (r&15)).
// dst stride = 128 shorts (NO pad; swizzle provides conflict-freedom for frag reads).
__device__ __forceinline__ void stage_swz(unsigned short* dst, const unsigned short* gbase,
                                          int gstride, int t){
  #pragma unroll
  for (int j=0;j<8;++j){
    int c = t + j*256;
    int r = c >> 4;
    int g = (c & 15) ^ (r & 15);
    gl16(gbase + (size_t)r*gstride + g*8, dst + (size_t)c*8);
  }
}

// ---------------- CSR build (multi-block 3-phase scan) ------------------------------------------
__global__ void k_zero(int* p, int n){ int i = blockIdx.x*blockDim.x+threadIdx.x; if(i<n) p[i]=0; }

__global__ void k_hist(const int* __restrict__ dst, int* __restrict__ cnt){
  int e = blockIdx.x*blockDim.x+threadIdx.x;
  if (e < EE) atomicAdd(&cnt[dst[e]], 1);
}

__global__ __launch_bounds__(256) void k_bsum(const int* __restrict__ cnt, int* __restrict__ bsum){
  int t = threadIdx.x;
  int i = blockIdx.x*256 + t;
  int v = (i < NN) ? cnt[i] : 0;
  #pragma unroll
  for (int off=32; off>0; off>>=1) v += __shfl_down(v, off);
  __shared__ int ws[4];
  if ((t & 63) == 0) ws[t>>6] = v;
  __syncthreads();
  if (t == 0) bsum[blockIdx.x] = ws[0]+ws[1]+ws[2]+ws[3];
}

__global__ __launch_bounds__(256) void k_bscan(const int* __restrict__ bsum,
                                               int* __restrict__ boff,
                                               int* __restrict__ row_ptr){
  __shared__ int part[256];
  int t = threadIdx.x;
  int v = (t < NB) ? bsum[t] : 0;
  part[t] = v;
  __syncthreads();
  for (int off=1; off<256; off<<=1){
    int u = (t>=off) ? part[t-off] : 0;
    __syncthreads();
    part[t] += u;
    __syncthreads();
  }
  if (t < NB) boff[t] = part[t] - v;
  if (t == 255) row_ptr[NN] = part[255];
}

__global__ __launch_bounds__(256) void k_bfinal(const int* __restrict__ cnt,
                                                const int* __restrict__ boff,
                                                int* __restrict__ row_ptr,
                                                int* __restrict__ cursor){
  __shared__ int part[256];
  int t = threadIdx.x;
  int i = blockIdx.x*256 + t;
  int v = (i < NN) ? cnt[i] : 0;
  part[t] = v;
  __syncthreads();
  for (int off=1; off<256; off<<=1){
    int u = (t>=off) ? part[t-off] : 0;
    __syncthreads();
    part[t] += u;
    __syncthreads();
  }
  if (i < NN){
    int p = boff[blockIdx.x] + part[t] - v;
    row_ptr[i] = p;
    cursor[i]  = p;
  }
}

__global__ void k_fill(const int* __restrict__ src, const int* __restrict__ dst,
                       int* __restrict__ cursor, int* __restrict__ csr_src){
  int e = blockIdx.x*blockDim.x+threadIdx.x;
  if (e >= EE) return;
  int d = dst[e];
  int p = atomicAdd(&cursor[d], 1);
  csr_src[p] = src[e];
}

// ---------------- weight transposes via LDS tiles (coalesced both sides) -----------------------
__global__ __launch_bounds__(256) void k_cvtw2(const float* __restrict__ Wf,
                                               const float* __restrict__ Wr,
                                               unsigned short* __restrict__ W2t){
  __shared__ float tile[64][65];
  int t = threadIdx.x;
  int n0 = blockIdx.x*64, k0 = blockIdx.y*64, l = blockIdx.z;
  const float* srcp = (n0 < 512) ? Wf : Wr;
  int nsrc = (n0 < 512) ? n0 : (n0 - 512);
  #pragma unroll
  for (int j=0;j<16;++j){
    int idx = t + j*256; int kk = idx>>6, nn = idx&63;
    tile[kk][nn] = srcp[(size_t)(l*128 + k0+kk)*512 + nsrc+nn];
  }
  __syncthreads();
  #pragma unroll
  for (int j=0;j<16;++j){
    int idx = t + j*256; int nn = idx>>6, kk = idx&63;
    W2t[((size_t)l*1024 + n0+nn)*128 + k0+kk] = f2bf(tile[kk][nn]);
  }
}
__global__ __launch_bounds__(256) void k_cvtwn(const float* __restrict__ Wn,
                                               unsigned short* __restrict__ Wnt){
  __shared__ float tile[64][65];
  int t = threadIdx.x;
  int n0 = blockIdx.x*64, k0 = blockIdx.y*64, l = blockIdx.z;
  #pragma unroll
  for (int j=0;j<16;++j){
    int idx = t + j*256; int kk = idx>>6, nn = idx&63;
    tile[kk][nn] = Wn[(size_t)(l*512 + k0+kk)*128 + n0+nn];
  }
  __syncthreads();
  #pragma unroll
  for (int j=0;j<16;++j){
    int idx = t + j*256; int nn = idx>>6, kk = idx&63;
    Wnt[((size_t)l*128 + n0+nn)*512 + k0+kk] = f2bf(tile[kk][nn]);
  }
}
__global__ void k_cvtx(const float* __restrict__ x, unsigned short* __restrict__ xb){
  int idx = blockIdx.x*blockDim.x + threadIdx.x;
  int row = idx >> 7;
  xb[idx] = (row < NN) ? f2bf(x[idx]) : (unsigned short)0;
}

// ---------------- shared epilogue helper (feat quant / logits), sC at 136-stride ---------------
__device__ __forceinline__ void feat_epilogue(const unsigned short* sC, float* sInv,
                                              const float* sAl, const float* sAr, int hd,
                                              int m0, int t,
                                              unsigned char* __restrict__ featQ,
                                              float2* __restrict__ elsc,
                                              float* __restrict__ erp){
  int r = t >> 1, half = t & 1;
  int base = half*64;
  float accl = 0.f, accr = 0.f, amax = 0.f;
  #pragma unroll
  for (int d=0; d<64; d+=4){
    uint2 u = *(const uint2*)&sC[r*136 + base + d];
    float f0=lo16(u.x), f1=hi16(u.x), f2=lo16(u.y), f3=hi16(u.y);
    float4 a  = *(const float4*)&sAl[hd*128 + base + d];
    float4 rr = *(const float4*)&sAr[hd*128 + base + d];
    accl += f0*a.x + f1*a.y + f2*a.z + f3*a.w;
    accr += f0*rr.x + f1*rr.y + f2*rr.z + f3*rr.w;
    amax = fmaxf(amax, fmaxf(fmaxf(fabsf(f0), fabsf(f1)), fmaxf(fabsf(f2), fabsf(f3))));
  }
  accl += __shfl_xor(accl, 1);
  accr += __shfl_xor(accr, 1);
  amax = fmaxf(amax, __shfl_xor(amax, 1));
  float am = fmaxf(amax, 1e-8f);
  if (half == 0){
    sInv[r] = 127.f / am;
    if ((m0+r) < NN){
      elsc[(size_t)(m0+r)*4 + hd] = make_float2(accl, am * (1.f/127.f));
      erp[(size_t)(m0+r)*4 + hd] = accr;
    }
  }
  __syncthreads();
  float qinv = sInv[r];
  unsigned char* qdst = featQ + (size_t)(m0+r)*512 + hd*128 + base;
  #pragma unroll
  for (int g=0; g<4; ++g){
    uint4 ua = *(const uint4*)&sC[r*136 + base + g*16];
    uint4 ub = *(const uint4*)&sC[r*136 + base + g*16 + 8];
    unsigned vals[8] = {ua.x, ua.y, ua.z, ua.w, ub.x, ub.y, ub.z, ub.w};
    unsigned p[4];
    #pragma unroll
    for (int j=0;j<4;++j){
      unsigned vlo = vals[2*j], vhi = vals[2*j+1];
      int q0 = (int)rintf(lo16(vlo)*qinv) + 128;
      int q1 = (int)rintf(hi16(vlo)*qinv) + 128;
      int q2 = (int)rintf(lo16(vhi)*qinv) + 128;
      int q3 = (int)rintf(hi16(vhi)*qinv) + 128;
      p[j] = (unsigned)q0 | ((unsigned)q1<<8) | ((unsigned)q2<<16) | ((unsigned)q3<<24);
    }
    *(uint4*)(qdst + g*16) = make_uint4(p[0],p[1],p[2],p[3]);
  }
}

// ---------------- GEMM1 (layer 0): async swizzled staging, A frags register-cached -------------
__global__ __launch_bounds__(256) void k_gemm1m(const unsigned short* __restrict__ xb,
                                                const unsigned short* __restrict__ W2t,
                                                const float* __restrict__ al,
                                                const float* __restrict__ ar,
                                                unsigned char* __restrict__ featQ,
                                                unsigned short* __restrict__ hbuf,
                                                float2* __restrict__ elsc,
                                                float* __restrict__ erp){
  __shared__ __attribute__((aligned(16))) unsigned short sA[128*136];
  __shared__ __attribute__((aligned(16))) unsigned short sB[128*136];
  __shared__ float sAl[512], sAr[512], sInv[128];
  int t = threadIdx.x;
  int m0 = blockIdx.x*128;
  int isRes = blockIdx.y;
  if (!isRes){
    sAl[t] = al[t]; sAl[256+t] = al[256+t];
    sAr[t] = ar[t]; sAr[256+t] = ar[256+t];
  }
  stage_swz(sA, xb + (size_t)m0*128, 128, t);
  __syncthreads();

  int lane = t & 63, w = t >> 6;
  int wm = (w & 1)*64, wn = (w >> 1)*64;
  int lrow = lane & 15, quad = lane >> 4;

  short8 af[4][4];                               // [kq][mt], swizzled reads
  #pragma unroll
  for (int kq=0;kq<4;++kq){
    int q = kq*4 + quad;
    #pragma unroll
    for (int mt=0;mt<4;++mt)
      af[kq][mt] = *(const short8*)(sA + (size_t)(wm+mt*16+lrow)*128 + ((q ^ lrow)*8));
  }

  for (int nb=0; nb<4; ++nb){
    int n0 = isRes*512 + nb*128;
    if (nb) __syncthreads();
    stage_swz(sB, W2t + (size_t)n0*128, 128, t);
    __syncthreads();

    f32x4 acc[4][4];
    #pragma unroll
    for (int mt=0;mt<4;++mt)
      #pragma unroll
      for (int nt=0;nt<4;++nt) acc[mt][nt] = (f32x4){0.f,0.f,0.f,0.f};

    #pragma unroll
    for (int kq=0;kq<4;++kq){
      int q = kq*4 + quad;
      short8 bf[4];
      #pragma unroll
      for (int nt=0;nt<4;++nt)
        bf[nt] = *(const short8*)(sB + (size_t)(wn+nt*16+lrow)*128 + ((q ^ lrow)*8));
      #pragma unroll
      for (int mt=0;mt<4;++mt)
        #pragma unroll
        for (int nt=0;nt<4;++nt)
          acc[mt][nt] = __builtin_amdgcn_mfma_f32_16x16x32_bf16(af[kq][mt], bf[nt], acc[mt][nt], 0,0,0);
    }

    __syncthreads();                             // MFMA reads of sB done -> reuse at 136-stride
    #pragma unroll
    for (int mt=0;mt<4;++mt)
      #pragma unroll
      for (int nt=0;nt<4;++nt)
        #pragma unroll
        for (int r=0;r<4;++r)
          sB[(wm+mt*16+quad*4+r)*136 + wn+nt*16+lrow] = f2bf(acc[mt][nt][r]);
    __syncthreads();

    if (isRes){
      #pragma unroll
      for (int j=0;j<8;++j){
        int c = t + j*256; int r = c>>4, kc = c&15;
        uint4 v = *(const uint4*)(sB + r*136 + kc*8);
        *(uint4*)(hbuf + (size_t)(m0+r)*512 + nb*128 + kc*8) = v;
      }
    } else {
      feat_epilogue(sB, sInv, sAl, sAr, nb, m0, t, featQ, elsc, erp);
    }
  }
}

// ---------------- edge softmax + aggregation: int8 gather, single pass, 4x unroll --------------
__global__ __launch_bounds__(256) void k_agg(const unsigned char* __restrict__ featQ,
                                             unsigned short* __restrict__ hbuf,
                                             const float2* __restrict__ elsc,
                                             const float* __restrict__ er,
                                             const int* __restrict__ row_ptr,
                                             const int* __restrict__ csr_src,
                                             const float* __restrict__ b_gat){
  int t = threadIdx.x;
  int lane = t & 63;
  int node = blockIdx.x*4 + (t>>6);
  int beg = row_ptr[node], end = row_ptr[node+1];
  int hd = lane >> 4;
  float erh = er[(size_t)node*4 + hd];

  float z = 0.f, sws = 0.f;
  float a0=0.f,a1=0.f,a2=0.f,a3=0.f,a4=0.f,a5=0.f,a6=0.f,a7=0.f;
  const uint2* fQ = (const uint2*)featQ;

  int i = beg;
  for (; i + 3 < end; i += 4){
    int s0 = csr_src[i], s1 = csr_src[i+1], s2 = csr_src[i+2], s3 = csr_src[i+3];
    float2 q0 = elsc[(size_t)s0*4 + hd];
    float2 q1 = elsc[(size_t)s1*4 + hd];
    float2 q2 = elsc[(size_t)s2*4 + hd];
    float2 q3 = elsc[(size_t)s3*4 + hd];
    uint2 f0 = fQ[(size_t)s0*64 + lane];
    uint2 f1 = fQ[(size_t)s1*64 + lane];
    uint2 f2 = fQ[(size_t)s2*64 + lane];
    uint2 f3 = fQ[(size_t)s3*64 + lane];
    float w0 = __expf(lk(q0.x + erh, 0.2f));
    float w1 = __expf(lk(q1.x + erh, 0.2f));
    float w2 = __expf(lk(q2.x + erh, 0.2f));
    float w3 = __expf(lk(q3.x + erh, 0.2f));
    float ws0 = w0*q0.y, ws1 = w1*q1.y, ws2 = w2*q2.y, ws3 = w3*q3.y;
    z += w0 + w1 + w2 + w3;
    sws += ws0 + ws1 + ws2 + ws3;
    a0 += ws0*(float)(f0.x & 255u)      + ws1*(float)(f1.x & 255u)      + ws2*(float)(f2.x & 255u)      + ws3*(float)(f3.x & 255u);
    a1 += ws0*(float)((f0.x>>8) & 255u) + ws1*(float)((f1.x>>8) & 255u) + ws2*(float)((f2.x>>8) & 255u) + ws3*(float)((f3.x>>8) & 255u);
    a2 += ws0*(float)((f0.x>>16)& 255u) + ws1*(float)((f1.x>>16)& 255u) + ws2*(float)((f2.x>>16)& 255u) + ws3*(float)((f3.x>>16)& 255u);
    a3 += ws0*(float)(f0.x>>24)         + ws1*(float)(f1.x>>24)         + ws2*(float)(f2.x>>24)         + ws3*(float)(f3.x>>24);
    a4 += ws0*(float)(f0.y & 255u)      + ws1*(float)(f1.y & 255u)      + ws2*(float)(f2.y & 255u)      + ws3*(float)(f3.y & 255u);
    a5 += ws0*(float)((f0.y>>8) & 255u) + ws1*(float)((f1.y>>8) & 255u) + ws2*(float)((f2.y>>8) & 255u) + ws3*(float)((f3.y>>8) & 255u);
    a6 += ws0*(float)((f0.y>>16)& 255u) + ws1*(float)((f1.y>>16)& 255u) + ws2*(float)((f2.y>>16)& 255u) + ws3*(float)((f3.y>>16)& 255u);
    a7 += ws0*(float)(f0.y>>24)         + ws1*(float)(f1.y>>24)         + ws2*(float)(f2.y>>24)         + ws3*(float)(f3.y>>24);
  }
  for (; i < end; ++i){
    int s = csr_src[i];
    float2 q = elsc[(size_t)s*4 + hd];
    uint2 f = fQ[(size_t)s*64 + lane];
    float w = __expf(lk(q.x + erh, 0.2f));
    float ws = w*q.y;
    z += w; sws += ws;
    a0 += ws*(float)(f.x & 255u);       a1 += ws*(float)((f.x>>8) & 255u);
    a2 += ws*(float)((f.x>>16) & 255u); a3 += ws*(float)(f.x>>24);
    a4 += ws*(float)(f.y & 255u);       a5 += ws*(float)((f.y>>8) & 255u);
    a6 += ws*(float)((f.y>>16) & 255u); a7 += ws*(float)(f.y>>24);
  }
  float iz = 1.f / fmaxf(z, 1e-20f);
  float off = 128.f * sws;

  uint4* rp = (uint4*)(hbuf + (size_t)node*HDIM) + lane;
  uint4 rv = *rp;
  const float4* bp = (const float4*)b_gat;
  float4 b1 = bp[2*lane], b2 = bp[2*lane+1];
  float o0 = lk((a0-off)*iz + lo16(rv.x) + b1.x, 0.01f);
  float o1 = lk((a1-off)*iz + hi16(rv.x) + b1.y, 0.01f);
  float o2 = lk((a2-off)*iz + lo16(rv.y) + b1.z, 0.01f);
  float o3 = lk((a3-off)*iz + hi16(rv.y) + b1.w, 0.01f);
  float o4 = lk((a4-off)*iz + lo16(rv.z) + b2.x, 0.01f);
  float o5 = lk((a5-off)*iz + hi16(rv.z) + b2.y, 0.01f);
  float o6 = lk((a6-off)*iz + lo16(rv.w) + b2.z, 0.01f);
  float o7 = lk((a7-off)*iz + hi16(rv.w) + b2.w, 0.01f);
  uint4 wv;
  wv.x = (unsigned)f2bf(o0) | ((unsigned)f2bf(o1) << 16);
  wv.y = (unsigned)f2bf(o2) | ((unsigned)f2bf(o3) << 16);
  wv.z = (unsigned)f2bf(o4) | ((unsigned)f2bf(o5) << 16);
  wv.w = (unsigned)f2bf(o6) | ((unsigned)f2bf(o7) << 16);
  *rp = wv;
}

// ---------------- FUSED: gemm3(l-1) + LN + gemm1(l), async swizzled staging --------------------
__global__ __launch_bounds__(256) void k_fused(unsigned short* __restrict__ hbuf,
                                               const unsigned short* __restrict__ Wnt,
                                               const float* __restrict__ bn,
                                               const float* __restrict__ lng,
                                               const float* __restrict__ lnb,
                                               const unsigned short* __restrict__ W2t,
                                               const float* __restrict__ al,
                                               const float* __restrict__ ar,
                                               unsigned char* __restrict__ featQ,
                                               float2* __restrict__ elsc,
                                               float* __restrict__ erp){
  __shared__ __attribute__((aligned(16))) unsigned short sA[128*136];
  __shared__ __attribute__((aligned(16))) unsigned short sB[128*136];
  __shared__ float sAl[512], sAr[512], sInv[128];
  int t = threadIdx.x;
  int m0 = blockIdx.x*128;
  sAl[t] = al[t]; sAl[256+t] = al[256+t];
  sAr[t] = ar[t]; sAr[256+t] = ar[256+t];
  int lane = t & 63, w = t >> 6;
  int wm = (w & 1)*64, wn = (w >> 1)*64;
  int lrow = lane & 15, quad = lane >> 4;

  // ---- phase 1: y = h @ Wnt (K=512), swizzled async staging ----
  f32x4 acc[4][4];
  #pragma unroll
  for (int mt=0;mt<4;++mt)
    #pragma unroll
    for (int nt=0;nt<4;++nt) acc[mt][nt] = (f32x4){0.f,0.f,0.f,0.f};

  for (int kc2=0; kc2<4; ++kc2){
    if (kc2) __syncthreads();
    stage_swz(sA, hbuf + (size_t)m0*512 + kc2*128, 512, t);
    stage_swz(sB, Wnt + (size_t)kc2*128, 512, t);
    __syncthreads();
    #pragma unroll
    for (int kq=0;kq<4;++kq){
      int q = kq*4 + quad;
      short8 a4[4], b4[4];
      #pragma unroll
      for (int mt=0;mt<4;++mt)
        a4[mt] = *(const short8*)(sA + (size_t)(wm+mt*16+lrow)*128 + ((q ^ lrow)*8));
      #pragma unroll
      for (int nt=0;nt<4;++nt)
        b4[nt] = *(const short8*)(sB + (size_t)(wn+nt*16+lrow)*128 + ((q ^ lrow)*8));
      #pragma unroll
      for (int mt=0;mt<4;++mt)
        #pragma unroll
        for (int nt=0;nt<4;++nt)
          acc[mt][nt] = __builtin_amdgcn_mfma_f32_16x16x32_bf16(a4[mt], b4[nt], acc[mt][nt], 0,0,0);
    }
  }

  // ---- phase 2: y(+bias) bf16 into sA at 136-stride (plain layout) ----
  float bnv[4];
  #pragma unroll
  for (int nt=0;nt<4;++nt) bnv[nt] = bn[wn + nt*16 + lrow];
  __syncthreads();
  #pragma unroll
  for (int mt=0;mt<4;++mt)
    #pragma unroll
    for (int nt=0;nt<4;++nt)
      #pragma unroll
      for (int r=0;r<4;++r)
        sA[(wm+mt*16+quad*4+r)*136 + wn+nt*16+lrow] = f2bf(acc[mt][nt][r] + bnv[nt]);
  __syncthreads();

  // ---- phase 3: LayerNorm in place (136-stride) ----
  float g0 = lng[lane], g1 = lng[64+lane];
  float bb0 = lnb[lane], bb1 = lnb[64+lane];
  for (int rr = w*32; rr < w*32+32; ++rr){
    float v0 = bf2f(sA[rr*136 + lane]), v1 = bf2f(sA[rr*136 + 64 + lane]);
    float s = v0 + v1;
    #pragma unroll
    for (int off=32; off>0; off>>=1) s += __shfl_xor(s, off);
    float mu = s * (1.f/128.f);
    float d0 = v0-mu, d1 = v1-mu;
    float q = d0*d0 + d1*d1;
    #pragma unroll
    for (int off=32; off>0; off>>=1) q += __shfl_xor(q, off);
    float inv = rsqrtf(q*(1.f/128.f) + 1e-5f);
    sA[rr*136 + lane]      = f2bf(d0*inv*g0 + bb0);
    sA[rr*136 + 64 + lane] = f2bf(d1*inv*g1 + bb1);
  }
  __syncthreads();

  // ---- phase 4: register-cache A fragments (136-stride, no swizzle) ----
  short8 af[4][4];
  #pragma unroll
  for (int kq=0;kq<4;++kq){
    int kb = kq*32 + quad*8;
    #pragma unroll
    for (int mt=0;mt<4;++mt) af[kq][mt] = *(const short8*)(sA + (wm+mt*16+lrow)*136 + kb);
  }

  // ---- phase 5: gemm1 over 8 N-tiles (0-3 feat, 4-7 res), swizzled async B staging ----
  for (int nb=0; nb<8; ++nb){
    stage_swz(sB, W2t + (size_t)nb*128*128, 128, t);
    __syncthreads();

    f32x4 ac2[4][4];
    #pragma unroll
    for (int mt=0;mt<4;++mt)
      #pragma unroll
      for (int nt=0;nt<4;++nt) ac2[mt][nt] = (f32x4){0.f,0.f,0.f,0.f};

    #pragma unroll
    for (int kq=0;kq<4;++kq){
      int q = kq*4 + quad;
      short8 b4[4];
      #pragma unroll
      for (int nt=0;nt<4;++nt)
        b4[nt] = *(const short8*)(sB + (size_t)(wn+nt*16+lrow)*128 + ((q ^ lrow)*8));
      #pragma unroll
      for (int mt=0;mt<4;++mt)
        #pragma unroll
        for (int nt=0;nt<4;++nt)
          ac2[mt][nt] = __builtin_amdgcn_mfma_f32_16x16x32_bf16(af[kq][mt], b4[nt], ac2[mt][nt], 0,0,0);
    }

    __syncthreads();
    #pragma unroll
    for (int mt=0;mt<4;++mt)
      #pragma unroll
      for (int nt=0;nt<4;++nt)
        #pragma unroll
        for (int r=0;r<4;++r)
          sB[(wm+mt*16+quad*4+r)*136 + wn+nt*16+lrow] = f2bf(ac2[mt][nt][r]);
    __syncthreads();

    if (nb >= 4){
      #pragma unroll
      for (int j=0;j<8;++j){
        int c = t + j*256; int r = c>>4, kc = c&15;
        uint4 v = *(const uint4*)(sB + r*136 + kc*8);
        *(uint4*)(hbuf + (size_t)(m0+r)*512 + (nb-4)*128 + kc*8) = v;
      }
    } else {
      feat_epilogue(sB, sInv, sAl, sAr, nb, m0, t, featQ, elsc, erp);
    }
    __syncthreads();
  }
}

// ---------------- GEMM3 (final layer) + LayerNorm; swizzled async staging ----------------------
__global__ __launch_bounds__(256) void k_gemm3m(const unsigned short* __restrict__ h,
                                                const unsigned short* __restrict__ Wnt,
                                                const float* __restrict__ bn,
                                                const float* __restrict__ lng,
                                                const float* __restrict__ lnb,
                                                float* __restrict__ out){
  __shared__ __attribute__((aligned(16))) char smem[2*128*136*2];
  unsigned short* sA = (unsigned short*)smem;
  unsigned short* sB = sA + 128*136;
  float* yf = (float*)smem;
  int t = threadIdx.x;
  int m0 = blockIdx.x*128;
  int lane = t & 63, w = t >> 6;
  int wm = (w & 1)*64, wn = (w >> 1)*64;
  int lrow = lane & 15, quad = lane >> 4;

  f32x4 acc[4][4];
  #pragma unroll
  for (int mt=0;mt<4;++mt)
    #pragma unroll
    for (int nt=0;nt<4;++nt) acc[mt][nt] = (f32x4){0.f,0.f,0.f,0.f};

  for (int kc2=0; kc2<4; ++kc2){
    if (kc2) __syncthreads();
    stage_swz(sA, h + (size_t)m0*512 + kc2*128, 512, t);
    stage_swz(sB, Wnt + (size_t)kc2*128, 512, t);
    __syncthreads();
    #pragma unroll
    for (int kq=0;kq<4;++kq){
      int q = kq*4 + quad;
      short8 a4[4], b4[4];
      #pragma unroll
      for (int mt=0;mt<4;++mt)
        a4[mt] = *(const short8*)(sA + (size_t)(wm+mt*16+lrow)*128 + ((q ^ lrow)*8));
      #pragma unroll
      for (int nt=0;nt<4;++nt)
        b4[nt] = *(const short8*)(sB + (size_t)(wn+nt*16+lrow)*128 + ((q ^ lrow)*8));
      #pragma unroll
      for (int mt=0;mt<4;++mt)
        #pragma unroll
        for (int nt=0;nt<4;++nt)
          acc[mt][nt] = __builtin_amdgcn_mfma_f32_16x16x32_bf16(a4[mt], b4[nt], acc[mt][nt], 0,0,0);
    }
  }

  float bnv[4];
  #pragma unroll
  for (int nt=0;nt<4;++nt) bnv[nt] = bn[wn + nt*16 + lrow];
  __syncthreads();
  #pragma unroll
  for (int mt=0;mt<4;++mt)
    #pragma unroll
    for (int nt=0;nt<4;++nt)
      #pragma unroll
      for (int r=0;r<4;++r)
        yf[(wm+mt*16+quad*4+r)*132 + wn+nt*16+lrow] = acc[mt][nt][r] + bnv[nt];
  __syncthreads();

  float g0 = lng[lane], g1 = lng[64+lane];
  float bb0 = lnb[lane], bb1 = lnb[64+lane];
  for (int rr = w*32; rr < w*32+32; ++rr){
    float v0 = yf[rr*132 + lane], v1 = yf[rr*132 + 64 + lane];
    float s = v0 + v1;
    #pragma unroll
    for (int off=32; off>0; off>>=1) s += __shfl_xor(s, off);
    float mu = s * (1.f/128.f);
    float d0 = v0-mu, d1 = v1-mu;
    float q = d0*d0 + d1*d1;
    #pragma unroll
    for (int off=32; off>0; off>>=1) q += __shfl_xor(q, off);
    float inv = rsqrtf(q*(1.f/128.f) + 1e-5f);
    int grow = m0 + rr;
    if (grow < NN){
      out[(size_t)grow*128 + lane]      = d0*inv*g0 + bb0;
      out[(size_t)grow*128 + 64 + lane] = d1*inv*g1 + bb1;
    }
  }
}

extern "C" void kernel_launch(void* const* d_in, const int* in_sizes, int n_in,
                              void* d_out, int out_size, void* d_ws, size_t ws_size,
                              hipStream_t stream){
  const float* features = (const float*)d_in[0];
  const int*   src      = (const int*)d_in[1];
  const int*   dst      = (const int*)d_in[2];
  const float* W_fc     = (const float*)d_in[3];
  const float* attn_l   = (const float*)d_in[4];
  const float* attn_r   = (const float*)d_in[5];
  const float* W_res    = (const float*)d_in[6];
  const float* b_gat    = (const float*)d_in[7];
  const float* W_nrm    = (const float*)d_in[8];
  const float* b_nrm    = (const float*)d_in[9];
  const float* ln_g     = (const float*)d_in[10];
  const float* ln_b     = (const float*)d_in[11];
  float* out = (float*)d_out;

  // workspace (~97 MB)
  unsigned short* xb    = (unsigned short*)d_ws;            // [NPAD,128] bf16 (layer-0 input)
  unsigned short* hbuf  = xb + (size_t)NPAD*128;            // [NPAD,512] bf16 (res -> h)
  unsigned short* W2t   = hbuf + (size_t)NPAD*512;          // [L,1024,128] bf16
  unsigned short* Wnt   = W2t + (size_t)LL*1024*128;        // [L,128,512] bf16
  unsigned char* featQ  = (unsigned char*)(Wnt + (size_t)LL*128*512);  // [NPAD,512] u8
  float2* elsc = (float2*)(featQ + (size_t)NPAD*512);       // [N,4] {el, scale}
  float* er = (float*)(elsc + (size_t)NN*4);                // [N,4]
  int* row_ptr = (int*)(er + (size_t)NN*4);                 // N+1
  int* cursor  = row_ptr + (NN+1);                          // N
  int* csr_src = cursor + NN;                               // E
  int* cnt     = csr_src + EE;                              // N
  int* bsum    = cnt + NN;                                  // NB
  int* boff    = bsum + NB;                                 // NB

  k_cvtw2<<<dim3(16, 2, LL), 256, 0, stream>>>(W_fc, W_res, W2t);
  k_cvtwn<<<dim3(2, 8, LL), 256, 0, stream>>>(W_nrm, Wnt);
  k_cvtx<<<(NPAD*128)/256, 256, 0, stream>>>(features, xb);
  k_zero<<<(NN+255)/256, 256, 0, stream>>>(cnt, NN);
  k_hist<<<(EE+255)/256, 256, 0, stream>>>(dst, cnt);
  k_bsum<<<NB, 256, 0, stream>>>(cnt, bsum);
  k_bscan<<<1, 256, 0, stream>>>(bsum, boff, row_ptr);
  k_bfinal<<<NB, 256, 0, stream>>>(cnt, boff, row_ptr, cursor);
  k_fill<<<(EE+255)/256, 256, 0, stream>>>(src, dst, cursor, csr_src);

  // layer 0: gemm1 from xb
  k_gemm1m<<<dim3(NPAD/128, 2), 256, 0, stream>>>(xb, W2t, attn_l, attn_r, featQ, hbuf, elsc, er);
  k_agg<<<NN/4, 256, 0, stream>>>(featQ, hbuf, elsc, er, row_ptr, csr_src, b_gat);

  // layers 1..3: fused gemm3(l-1)+LN(l-1)+gemm1(l), then agg(l)
  for (int l=1; l<LL; ++l){
    k_fused<<<NPAD/128, 256, 0, stream>>>(hbuf,
        Wnt + (size_t)(l-1)*128*512, b_nrm + (size_t)(l-1)*DD,
        ln_g + (size_t)(l-1)*DD, ln_b + (size_t)(l-1)*DD,
        W2t + (size_t)l*1024*128, attn_l + (size_t)l*HH*DD, attn_r + (size_t)l*HH*DD,
        featQ, elsc, er);
    k_agg<<<NN/4, 256, 0, stream>>>(featQ, hbuf, elsc, er, row_ptr, csr_src,
                                    b_gat + (size_t)l*HDIM);
  }

  // final gemm3 + LN -> out (fp32)
  k_gemm3m<<<NPAD/128, 256, 0, stream>>>(hbuf, Wnt + (size_t)3*128*512,
                                         b_nrm + (size_t)3*DD, ln_g + (size_t)3*DD,
                                         ln_b + (size_t)3*DD, out);
}